// Round 1
// baseline (804.141 us; speedup 1.0000x reference)
//
#include <hip/hip_runtime.h>
#include <math.h>

#define NN   50000
#define EE   800000
#define EF   850000   // EE + NN self loops
#define HH   128
#define FE   16
#define LATD 64
#define MAXNN 200

#define ADJ_TOT   10000000   // NN*MAXNN
#define NODES_TOT 6400000    // NN*HH
#define OUT_TOT   16400000   // ADJ_TOT + NODES_TOT
#define MU_OFF    16400000
#define LV_OFF    16400064

// ---------------- init ----------------
__global__ void kinit(int* ideg, int* fill, float* etsum1, float* etsum2, float* hgsum){
  int i = blockIdx.x*blockDim.x + threadIdx.x;
  if(i < NN){ ideg[i]=0; fill[i]=0; etsum1[i]=0.f; etsum2[i]=0.f; }
  if(i < HH) hgsum[i]=0.f;
}

// wa[f] = sum_j We[f][j]*att_e[j]   (fold edge-MLP into 16-vector)
__global__ void kwa(const float* We1, const float* ae1, const float* We2, const float* ae2,
                    float* wa1, float* wa2){
  int t = threadIdx.x;
  if(t < FE){
    float s1=0.f, s2=0.f;
    for(int j=0;j<HH;j++){ s1 += We1[t*HH+j]*ae1[j]; s2 += We2[t*HH+j]*ae2[j]; }
    wa1[t]=s1; wa2[t]=s2;
  }
}

__global__ void kdeg(const int* __restrict__ ei, int* ideg){
  int e = blockIdx.x*blockDim.x + threadIdx.x;
  if(e<EE) atomicAdd(&ideg[ei[EE+e]], 1);
}

// ---------------- exclusive scan of rowlen = ideg+1 ----------------
__global__ void kscan1(const int* __restrict__ ideg, int* rowstart, int* blocksum){
  __shared__ int sd[1024];
  int t=threadIdx.x; int i=blockIdx.x*1024+t;
  int v = (i<NN)? (ideg[i]+1) : 0;
  sd[t]=v; __syncthreads();
  for(int off=1; off<1024; off<<=1){
    int x = (t>=off)? sd[t-off] : 0;
    __syncthreads();
    sd[t] += x;
    __syncthreads();
  }
  if(i<NN) rowstart[i] = sd[t]-v;
  if(t==1023) blocksum[blockIdx.x]=sd[1023];
}
__global__ void kscan2(const int* blocksum, int* blockoff, int nb){
  if(threadIdx.x==0){
    int run=0;
    for(int b=0;b<nb;b++){ blockoff[b]=run; run+=blocksum[b]; }
    blockoff[nb]=run;
  }
}
__global__ void kscan3(int* rowstart, const int* __restrict__ blockoff, int nb){
  int i=blockIdx.x*blockDim.x+threadIdx.x;
  if(i<NN) rowstart[i]+=blockoff[i>>10];
  if(i==0) rowstart[NN]=blockoff[nb];
}

// ---------------- CSR scatter + per-edge et scalars ----------------
__global__ void kscatter(const int* __restrict__ ei, const float* __restrict__ ea,
                         const float* __restrict__ wa1, const float* __restrict__ wa2,
                         const int* __restrict__ rowstart, int* fill,
                         int* csr_src, float* csr_et1, float* csr_et2,
                         float* etsum1, float* etsum2){
  int e=blockIdx.x*blockDim.x+threadIdx.x;
  if(e>=EE) return;
  int s=ei[e], d=ei[EE+e];
  float d1=0.f,d2=0.f;
  #pragma unroll
  for(int f=0;f<FE;f++){ float v=ea[e*FE+f]; d1+=v*wa1[f]; d2+=v*wa2[f]; }
  int pos = rowstart[d] + atomicAdd(&fill[d],1);
  csr_src[pos]=s; csr_et1[pos]=d1; csr_et2[pos]=d2;
  atomicAdd(&etsum1[d],d1); atomicAdd(&etsum2[d],d2);
}

__global__ void kself(const int* __restrict__ rowstart, const int* __restrict__ ideg,
                      int* csr_src, float* csr_et1, float* csr_et2,
                      const float* __restrict__ etsum1, const float* __restrict__ etsum2){
  int i=blockIdx.x*blockDim.x+threadIdx.x;
  if(i>=NN) return;
  int pos = rowstart[i]+ideg[i];
  float dg = (float)ideg[i]; if(dg<1.f) dg=1.f;
  csr_src[pos]=i;
  csr_et1[pos]=etsum1[i]/dg;
  csr_et2[pos]=etsum2[i]/dg;
}

// ---------------- g = h @ W ; asrc = g.att_src ; adst = g.att_dst ----------------
__global__ __launch_bounds__(128) void kgemm(const float* __restrict__ hin, const float* __restrict__ W,
             const float* __restrict__ atts, const float* __restrict__ attd,
             float* __restrict__ G, float* __restrict__ asrc, float* __restrict__ adst){
  int i=blockIdx.x; int t=threadIdx.x;
  __shared__ float hrow[HH];
  __shared__ float red[HH];
  hrow[t]=hin[(size_t)i*HH+t];
  __syncthreads();
  float acc=0.f;
  #pragma unroll 16
  for(int k=0;k<HH;k++) acc += hrow[k]*W[k*HH+t];
  G[(size_t)i*HH+t]=acc;
  red[t]=acc*atts[t]; __syncthreads();
  for(int off=64;off>0;off>>=1){ if(t<off) red[t]+=red[t+off]; __syncthreads(); }
  if(t==0) asrc[i]=red[0];
  __syncthreads();
  red[t]=acc*attd[t]; __syncthreads();
  for(int off=64;off>0;off>>=1){ if(t<off) red[t]+=red[t+off]; __syncthreads(); }
  if(t==0) adst[i]=red[0];
}

// ---------------- GAT softmax-aggregate, one block per dst node ----------------
__global__ __launch_bounds__(128) void kgat(const float* __restrict__ A,
    const float* __restrict__ asrc, const float* __restrict__ adst,
    const int* __restrict__ rowstart, const int* __restrict__ csr_src,
    const float* __restrict__ csr_et, const float* __restrict__ bias,
    float* __restrict__ alphabuf, float* __restrict__ Bout){
  int i = blockIdx.x; int t = threadIdx.x;
  int base = rowstart[i]; int len = rowstart[i+1]-base;
  __shared__ float red[HH];
  __shared__ float sal[1024];
  bool inlds = (len <= 1024);
  float adi = adst[i];
  // phase 1: alpha + row max
  float lmax = -1e30f;
  for(int k=t;k<len;k+=HH){
    int s = csr_src[base+k];
    float a = asrc[s] + adi + csr_et[base+k];
    a = a>0.f ? a : 0.2f*a;            // leaky_relu 0.2
    if(inlds) sal[k]=a; else alphabuf[base+k]=a;
    lmax = fmaxf(lmax,a);
  }
  red[t]=lmax; __syncthreads();
  for(int off=64;off>0;off>>=1){ if(t<off) red[t]=fmaxf(red[t],red[t+off]); __syncthreads(); }
  float m = red[0];
  __syncthreads();
  // phase 2: exp + sum
  float lsum=0.f;
  for(int k=t;k<len;k+=HH){
    float a = inlds ? sal[k] : alphabuf[base+k];
    float ex = __expf(a-m);
    if(inlds) sal[k]=ex; else alphabuf[base+k]=ex;
    lsum += ex;
  }
  red[t]=lsum; __syncthreads();
  for(int off=64;off>0;off>>=1){ if(t<off) red[t]+=red[t+off]; __syncthreads(); }
  float den = red[0];
  __syncthreads();
  // phase 3: weighted gather of g[src] rows (coalesced 512B per edge)
  float acc=0.f;
  for(int k=0;k<len;k++){
    float w = inlds ? sal[k] : alphabuf[base+k];
    int s = csr_src[base+k];
    acc += w * A[(size_t)s*HH+t];
  }
  Bout[(size_t)i*HH+t] = fmaxf(acc/den + bias[t], 0.f);
}

// ---------------- column mean partials ----------------
__global__ __launch_bounds__(128) void khg(const float* __restrict__ B, float* hgsum){
  int f=threadIdx.x; int b=blockIdx.x; int nb=gridDim.x;
  int chunk=(NN+nb-1)/nb;
  int i0=b*chunk, i1=min(i0+chunk, NN);
  float s=0.f;
  for(int i=i0;i<i1;i++) s += B[(size_t)i*HH+f];
  atomicAdd(&hgsum[f], s);
}

// ---------------- tiny decoder, single block ----------------
__global__ __launch_bounds__(256) void kdec(const float* __restrict__ hgsum, const float* __restrict__ eps,
   const float* muW,const float* mub,const float* lvW,const float* lvb,
   const float* decW,const float* decb,
   const float* aW1,const float* ab1,const float* aW2,const float* ab2,
   const float* nW1,const float* nb1,const float* nW2,const float* nb2,
   float* out, float* rowadj, float* rownodes){
  __shared__ float hg[HH], z[LATD], hd[HH], t1[HH], t2[HH];
  int t=threadIdx.x;
  if(t<HH) hg[t]=hgsum[t]*(1.0f/NN);
  __syncthreads();
  if(t<LATD){
    float mu=mub[t], lv=lvb[t];
    for(int k=0;k<HH;k++){ mu += hg[k]*muW[k*LATD+t]; lv += hg[k]*lvW[k*LATD+t]; }
    out[MU_OFF+t]=mu; out[LV_OFF+t]=lv;
    z[t]=mu + eps[t]*expf(0.5f*lv);
  }
  __syncthreads();
  if(t<HH){
    float a=decb[t];
    for(int k=0;k<LATD;k++) a += z[k]*decW[k*HH+t];
    hd[t]=fmaxf(a,0.f);
  }
  __syncthreads();
  if(t<HH){
    float a=ab1[t];
    for(int k=0;k<HH;k++) a += hd[k]*aW1[k*HH+t];
    t1[t]=fmaxf(a,0.f);
  } else {
    int j=t-HH;
    float a=nb1[j];
    for(int k=0;k<HH;k++) a += hd[k]*nW1[k*HH+j];
    t2[j]=fmaxf(a,0.f);
  }
  __syncthreads();
  for(int j=t;j<MAXNN;j+=256){
    float a=ab2[j];
    for(int k=0;k<HH;k++) a += t1[k]*aW2[k*MAXNN+j];
    rowadj[j]=a;
  }
  if(t<HH){
    float a=nb2[t];
    for(int k=0;k<HH;k++) a += t2[k]*nW2[k*HH+t];
    rownodes[t]=a;
  }
}

// ---------------- broadcast the two decoder rows over all N nodes ----------------
__global__ __launch_bounds__(256) void kbcast(const float* __restrict__ rowadj,
                                              const float* __restrict__ rownodes,
                                              float* __restrict__ out){
  __shared__ float row[MAXNN+HH];
  int t=threadIdx.x;
  if(t<MAXNN) row[t]=rowadj[t];
  if(t<HH) row[MAXNN+t]=rownodes[t];
  __syncthreads();
  int stride=gridDim.x*blockDim.x;
  for(int idx=blockIdx.x*blockDim.x+t; idx<OUT_TOT; idx+=stride){
    if(idx<ADJ_TOT) out[idx]=row[idx%MAXNN];
    else { int j=(idx-ADJ_TOT)&(HH-1); out[idx]=row[MAXNN+j]; }
  }
}

extern "C" void kernel_launch(void* const* d_in, const int* in_sizes, int n_in,
                              void* d_out, int out_size, void* d_ws, size_t ws_size,
                              hipStream_t stream){
  const float* x   = (const float*)d_in[0];
  const int*   ei  = (const int*)d_in[1];
  const float* ea  = (const float*)d_in[2];
  const float* eps = (const float*)d_in[3];
  const float* W1  =(const float*)d_in[5];
  const float* as1 =(const float*)d_in[6];
  const float* ad1 =(const float*)d_in[7];
  const float* We1 =(const float*)d_in[8];
  const float* ae1 =(const float*)d_in[9];
  const float* b1  =(const float*)d_in[10];
  const float* W2  =(const float*)d_in[11];
  const float* as2 =(const float*)d_in[12];
  const float* ad2 =(const float*)d_in[13];
  const float* We2 =(const float*)d_in[14];
  const float* ae2 =(const float*)d_in[15];
  const float* b2  =(const float*)d_in[16];
  const float* muW =(const float*)d_in[17];
  const float* mub =(const float*)d_in[18];
  const float* lvW =(const float*)d_in[19];
  const float* lvb =(const float*)d_in[20];
  const float* decW=(const float*)d_in[21];
  const float* decb=(const float*)d_in[22];
  const float* aW1 =(const float*)d_in[23];
  const float* ab1 =(const float*)d_in[24];
  const float* aW2 =(const float*)d_in[25];
  const float* ab2 =(const float*)d_in[26];
  const float* nW1 =(const float*)d_in[27];
  const float* nb1 =(const float*)d_in[28];
  const float* nW2 =(const float*)d_in[29];
  const float* nb2 =(const float*)d_in[30];
  float* out=(float*)d_out;

  char* w=(char*)d_ws;
  float* A        = (float*)w; w += (size_t)NN*HH*4;
  float* Bb       = (float*)w; w += (size_t)NN*HH*4;
  float* cet1     = (float*)w; w += (size_t)EF*4;
  float* cet2     = (float*)w; w += (size_t)EF*4;
  float* alphabuf = (float*)w; w += (size_t)EF*4;
  int*   csrc     = (int*)w;   w += (size_t)EF*4;
  int*   rowstart = (int*)w;   w += (size_t)(NN+1)*4;
  int*   fill     = (int*)w;   w += (size_t)NN*4;
  int*   ideg     = (int*)w;   w += (size_t)NN*4;
  float* etsum1   = (float*)w; w += (size_t)NN*4;
  float* etsum2   = (float*)w; w += (size_t)NN*4;
  float* asrc     = (float*)w; w += (size_t)NN*4;
  float* adst     = (float*)w; w += (size_t)NN*4;
  float* hgsum    = (float*)w; w += 128*4;
  float* wa1      = (float*)w; w += 16*4;
  float* wa2      = (float*)w; w += 16*4;
  float* rowadj   = (float*)w; w += 256*4;
  float* rownodes = (float*)w; w += 128*4;
  int*   blocksum = (int*)w;   w += 64*4;
  int*   blockoff = (int*)w;   w += 64*4;

  int nb = (NN+1023)/1024; // 49

  hipLaunchKernelGGL(kinit, dim3((NN+255)/256), dim3(256), 0, stream, ideg, fill, etsum1, etsum2, hgsum);
  hipLaunchKernelGGL(kwa, dim3(1), dim3(64), 0, stream, We1, ae1, We2, ae2, wa1, wa2);
  hipLaunchKernelGGL(kdeg, dim3((EE+255)/256), dim3(256), 0, stream, ei, ideg);
  hipLaunchKernelGGL(kscan1, dim3(nb), dim3(1024), 0, stream, ideg, rowstart, blocksum);
  hipLaunchKernelGGL(kscan2, dim3(1), dim3(64), 0, stream, blocksum, blockoff, nb);
  hipLaunchKernelGGL(kscan3, dim3((NN+255)/256), dim3(256), 0, stream, rowstart, blockoff, nb);
  hipLaunchKernelGGL(kscatter, dim3((EE+255)/256), dim3(256), 0, stream,
                     ei, ea, wa1, wa2, rowstart, fill, csrc, cet1, cet2, etsum1, etsum2);
  hipLaunchKernelGGL(kself, dim3((NN+255)/256), dim3(256), 0, stream,
                     rowstart, ideg, csrc, cet1, cet2, etsum1, etsum2);
  // layer 1
  hipLaunchKernelGGL(kgemm, dim3(NN), dim3(128), 0, stream, x,  W1, as1, ad1, A, asrc, adst);
  hipLaunchKernelGGL(kgat,  dim3(NN), dim3(128), 0, stream, A, asrc, adst, rowstart, csrc, cet1, b1, alphabuf, Bb);
  // layer 2
  hipLaunchKernelGGL(kgemm, dim3(NN), dim3(128), 0, stream, Bb, W2, as2, ad2, A, asrc, adst);
  hipLaunchKernelGGL(kgat,  dim3(NN), dim3(128), 0, stream, A, asrc, adst, rowstart, csrc, cet2, b2, alphabuf, Bb);
  // graph embedding + decoder + broadcast
  hipLaunchKernelGGL(khg,   dim3(256), dim3(128), 0, stream, Bb, hgsum);
  hipLaunchKernelGGL(kdec,  dim3(1), dim3(256), 0, stream, hgsum, eps,
                     muW,mub,lvW,lvb,decW,decb,aW1,ab1,aW2,ab2,nW1,nb1,nW2,nb2,
                     out, rowadj, rownodes);
  hipLaunchKernelGGL(kbcast, dim3(2048), dim3(256), 0, stream, rowadj, rownodes, out);
}

// Round 2
// 663.598 us; speedup vs baseline: 1.2118x; 1.2118x over previous
//
#include <hip/hip_runtime.h>
#include <math.h>

#define NN   50000
#define EE   800000
#define EF   850000   // EE + NN self loops
#define HH   128
#define FE   16
#define LATD 64
#define MAXNN 200

#define ADJ_TOT   10000000   // NN*MAXNN
#define NODES_TOT 6400000    // NN*HH
#define OUT_TOT   16400000   // ADJ_TOT + NODES_TOT
#define MU_OFF    16400000
#define LV_OFF    16400064

// ---------------- init ----------------
__global__ void kinit(int* ideg, int* fill, float* etsum1, float* etsum2, float* hgsum){
  int i = blockIdx.x*blockDim.x + threadIdx.x;
  if(i < NN){ ideg[i]=0; fill[i]=0; etsum1[i]=0.f; etsum2[i]=0.f; }
  if(i < HH) hgsum[i]=0.f;
}

// wa[f] = sum_j We[f][j]*att_e[j]   (fold edge-MLP into 16-vector)
__global__ void kwa(const float* We1, const float* ae1, const float* We2, const float* ae2,
                    float* wa1, float* wa2){
  int t = threadIdx.x;
  if(t < FE){
    float s1=0.f, s2=0.f;
    for(int j=0;j<HH;j++){ s1 += We1[t*HH+j]*ae1[j]; s2 += We2[t*HH+j]*ae2[j]; }
    wa1[t]=s1; wa2[t]=s2;
  }
}

__global__ void kdeg(const int* __restrict__ ei, int* ideg){
  int e = blockIdx.x*blockDim.x + threadIdx.x;
  if(e<EE) atomicAdd(&ideg[ei[EE+e]], 1);
}

// ---------------- exclusive scan of rowlen = ideg+1 ----------------
__global__ void kscan1(const int* __restrict__ ideg, int* rowstart, int* blocksum){
  __shared__ int sd[1024];
  int t=threadIdx.x; int i=blockIdx.x*1024+t;
  int v = (i<NN)? (ideg[i]+1) : 0;
  sd[t]=v; __syncthreads();
  for(int off=1; off<1024; off<<=1){
    int x = (t>=off)? sd[t-off] : 0;
    __syncthreads();
    sd[t] += x;
    __syncthreads();
  }
  if(i<NN) rowstart[i] = sd[t]-v;
  if(t==1023) blocksum[blockIdx.x]=sd[1023];
}
__global__ void kscan2(const int* blocksum, int* blockoff, int nb){
  if(threadIdx.x==0){
    int run=0;
    for(int b=0;b<nb;b++){ blockoff[b]=run; run+=blocksum[b]; }
    blockoff[nb]=run;
  }
}
__global__ void kscan3(int* rowstart, const int* __restrict__ blockoff, int nb){
  int i=blockIdx.x*blockDim.x+threadIdx.x;
  if(i<NN) rowstart[i]+=blockoff[i>>10];
  if(i==0) rowstart[NN]=blockoff[nb];
}

// ---------------- CSR scatter + per-edge et scalars ----------------
__global__ void kscatter(const int* __restrict__ ei, const float* __restrict__ ea,
                         const float* __restrict__ wa1, const float* __restrict__ wa2,
                         const int* __restrict__ rowstart, int* fill,
                         int* csr_src, float* csr_et1, float* csr_et2,
                         float* etsum1, float* etsum2){
  int e=blockIdx.x*blockDim.x+threadIdx.x;
  if(e>=EE) return;
  int s=ei[e], d=ei[EE+e];
  float d1=0.f,d2=0.f;
  #pragma unroll
  for(int f=0;f<FE;f++){ float v=ea[e*FE+f]; d1+=v*wa1[f]; d2+=v*wa2[f]; }
  int pos = rowstart[d] + atomicAdd(&fill[d],1);
  csr_src[pos]=s; csr_et1[pos]=d1; csr_et2[pos]=d2;
  atomicAdd(&etsum1[d],d1); atomicAdd(&etsum2[d],d2);
}

__global__ void kself(const int* __restrict__ rowstart, const int* __restrict__ ideg,
                      int* csr_src, float* csr_et1, float* csr_et2,
                      const float* __restrict__ etsum1, const float* __restrict__ etsum2){
  int i=blockIdx.x*blockDim.x+threadIdx.x;
  if(i>=NN) return;
  int pos = rowstart[i]+ideg[i];
  float dg = (float)ideg[i]; if(dg<1.f) dg=1.f;
  csr_src[pos]=i;
  csr_et1[pos]=etsum1[i]/dg;
  csr_et2[pos]=etsum2[i]/dg;
}

// ---------------- tiled fp32 GEMM: G = h @ W, plus asrc/adst row dots ----------------
// block: 256 threads; tile: 128 rows x 128 cols; thread micro-tile 8x8.
// h tile staged in LDS (64 KB) with XOR swizzle on k-quads -> conflict-free b128.
__global__ __launch_bounds__(256) void kgemm2(const float* __restrict__ hin,
    const float* __restrict__ W,
    const float* __restrict__ atts, const float* __restrict__ attd,
    float* __restrict__ G, float* __restrict__ asrc, float* __restrict__ adst){
  __shared__ float hs[128*128];   // 64 KB, stride 128 dwords, swizzled
  int t = threadIdx.x;
  int row0 = blockIdx.x * 128;
  // ---- stage h tile (swizzled: float4-chunk c4 stored at c4 ^ ((row>>3)&3)) ----
  #pragma unroll
  for(int it=0; it<16; ++it){
    int f = it*256 + t;          // float4 index 0..4095
    int r = f >> 5;              // 32 float4-chunks per row
    int c4 = f & 31;
    int grow = row0 + r;
    float4 v = make_float4(0.f,0.f,0.f,0.f);
    if(grow < NN) v = *(const float4*)(hin + (size_t)grow*HH + c4*4);
    int sc4 = c4 ^ ((r>>3)&3);
    *(float4*)(hs + r*HH + sc4*4) = v;
  }
  __syncthreads();

  int tcg = t & 15;              // col group: cols c0..c0+7
  int trg = t >> 4;              // row group: rows r0..r0+7
  int c0  = tcg*8;
  int r0  = trg*8;
  int sw  = trg & 3;             // read-side swizzle

  float s_att[8], d_att[8];
  #pragma unroll
  for(int c=0;c<8;c++){ s_att[c]=atts[c0+c]; d_att[c]=attd[c0+c]; }

  float acc[8][8];
  #pragma unroll
  for(int r=0;r<8;r++)
    #pragma unroll
    for(int c=0;c<8;c++) acc[r][c]=0.f;

  for(int k=0;k<HH;k+=4){
    int k4 = k>>2;
    float4 hv[8];
    #pragma unroll
    for(int r=0;r<8;r++)
      hv[r] = *(const float4*)(hs + (r0+r)*HH + ((k4 ^ sw)<<2));
    #pragma unroll
    for(int kk=0;kk<4;kk++){
      float4 w0 = *(const float4*)(W + (size_t)(k+kk)*HH + c0);
      float4 w1 = *(const float4*)(W + (size_t)(k+kk)*HH + c0 + 4);
      float wz[8] = {w0.x,w0.y,w0.z,w0.w,w1.x,w1.y,w1.z,w1.w};
      #pragma unroll
      for(int r=0;r<8;r++){
        float hval = (kk==0)?hv[r].x : (kk==1)?hv[r].y : (kk==2)?hv[r].z : hv[r].w;
        #pragma unroll
        for(int c=0;c<8;c++) acc[r][c] += hval * wz[c];
      }
    }
  }

  // ---- store G + row-dot epilogue ----
  #pragma unroll
  for(int r=0;r<8;r++){
    int grow = row0 + r0 + r;
    float ps=0.f, pd=0.f;
    #pragma unroll
    for(int c=0;c<8;c++){ ps += acc[r][c]*s_att[c]; pd += acc[r][c]*d_att[c]; }
    #pragma unroll
    for(int m=8;m>=1;m>>=1){ ps += __shfl_xor(ps,m,16); pd += __shfl_xor(pd,m,16); }
    if(grow < NN){
      float4 o0 = make_float4(acc[r][0],acc[r][1],acc[r][2],acc[r][3]);
      float4 o1 = make_float4(acc[r][4],acc[r][5],acc[r][6],acc[r][7]);
      *(float4*)(G + (size_t)grow*HH + c0)     = o0;
      *(float4*)(G + (size_t)grow*HH + c0 + 4) = o1;
      if(tcg==0){ asrc[grow]=ps; adst[grow]=pd; }
    }
  }
}

// ---------------- GAT softmax-aggregate, one block per dst node ----------------
__global__ __launch_bounds__(128) void kgat(const float* __restrict__ A,
    const float* __restrict__ asrc, const float* __restrict__ adst,
    const int* __restrict__ rowstart, const int* __restrict__ csr_src,
    const float* __restrict__ csr_et, const float* __restrict__ bias,
    float* __restrict__ alphabuf, float* __restrict__ Bout){
  int i = blockIdx.x; int t = threadIdx.x;
  int base = rowstart[i]; int len = rowstart[i+1]-base;
  __shared__ float red[HH];
  __shared__ float sal[1024];
  bool inlds = (len <= 1024);
  float adi = adst[i];
  // phase 1: alpha + row max
  float lmax = -1e30f;
  for(int k=t;k<len;k+=HH){
    int s = csr_src[base+k];
    float a = asrc[s] + adi + csr_et[base+k];
    a = a>0.f ? a : 0.2f*a;            // leaky_relu 0.2
    if(inlds) sal[k]=a; else alphabuf[base+k]=a;
    lmax = fmaxf(lmax,a);
  }
  red[t]=lmax; __syncthreads();
  for(int off=64;off>0;off>>=1){ if(t<off) red[t]=fmaxf(red[t],red[t+off]); __syncthreads(); }
  float m = red[0];
  __syncthreads();
  // phase 2: exp + sum
  float lsum=0.f;
  for(int k=t;k<len;k+=HH){
    float a = inlds ? sal[k] : alphabuf[base+k];
    float ex = __expf(a-m);
    if(inlds) sal[k]=ex; else alphabuf[base+k]=ex;
    lsum += ex;
  }
  red[t]=lsum; __syncthreads();
  for(int off=64;off>0;off>>=1){ if(t<off) red[t]+=red[t+off]; __syncthreads(); }
  float den = red[0];
  __syncthreads();
  // phase 3: weighted gather of g[src] rows (coalesced 512B per edge)
  float acc=0.f;
  for(int k=0;k<len;k++){
    float w = inlds ? sal[k] : alphabuf[base+k];
    int s = csr_src[base+k];
    acc += w * A[(size_t)s*HH+t];
  }
  Bout[(size_t)i*HH+t] = fmaxf(acc/den + bias[t], 0.f);
}

// ---------------- column mean partials ----------------
__global__ __launch_bounds__(128) void khg(const float* __restrict__ B, float* hgsum){
  int f=threadIdx.x; int b=blockIdx.x; int nb=gridDim.x;
  int chunk=(NN+nb-1)/nb;
  int i0=b*chunk, i1=min(i0+chunk, NN);
  float s=0.f;
  for(int i=i0;i<i1;i++) s += B[(size_t)i*HH+f];
  atomicAdd(&hgsum[f], s);
}

// ---------------- tiny decoder, single block ----------------
__global__ __launch_bounds__(256) void kdec(const float* __restrict__ hgsum, const float* __restrict__ eps,
   const float* muW,const float* mub,const float* lvW,const float* lvb,
   const float* decW,const float* decb,
   const float* aW1,const float* ab1,const float* aW2,const float* ab2,
   const float* nW1,const float* nb1,const float* nW2,const float* nb2,
   float* out, float* rowadj, float* rownodes){
  __shared__ float hg[HH], z[LATD], hd[HH], t1[HH], t2[HH];
  int t=threadIdx.x;
  if(t<HH) hg[t]=hgsum[t]*(1.0f/NN);
  __syncthreads();
  if(t<LATD){
    float mu=mub[t], lv=lvb[t];
    for(int k=0;k<HH;k++){ mu += hg[k]*muW[k*LATD+t]; lv += hg[k]*lvW[k*LATD+t]; }
    out[MU_OFF+t]=mu; out[LV_OFF+t]=lv;
    z[t]=mu + eps[t]*expf(0.5f*lv);
  }
  __syncthreads();
  if(t<HH){
    float a=decb[t];
    for(int k=0;k<LATD;k++) a += z[k]*decW[k*HH+t];
    hd[t]=fmaxf(a,0.f);
  }
  __syncthreads();
  if(t<HH){
    float a=ab1[t];
    for(int k=0;k<HH;k++) a += hd[k]*aW1[k*HH+t];
    t1[t]=fmaxf(a,0.f);
  } else {
    int j=t-HH;
    float a=nb1[j];
    for(int k=0;k<HH;k++) a += hd[k]*nW1[k*HH+j];
    t2[j]=fmaxf(a,0.f);
  }
  __syncthreads();
  for(int j=t;j<MAXNN;j+=256){
    float a=ab2[j];
    for(int k=0;k<HH;k++) a += t1[k]*aW2[k*MAXNN+j];
    rowadj[j]=a;
  }
  if(t<HH){
    float a=nb2[t];
    for(int k=0;k<HH;k++) a += t2[k]*nW2[k*HH+t];
    rownodes[t]=a;
  }
}

// ---------------- broadcast the two decoder rows over all N nodes ----------------
__global__ __launch_bounds__(256) void kbcast(const float* __restrict__ rowadj,
                                              const float* __restrict__ rownodes,
                                              float* __restrict__ out){
  __shared__ float row[MAXNN+HH];
  int t=threadIdx.x;
  if(t<MAXNN) row[t]=rowadj[t];
  if(t<HH) row[MAXNN+t]=rownodes[t];
  __syncthreads();
  int stride=gridDim.x*blockDim.x;
  for(int idx=blockIdx.x*blockDim.x+t; idx<OUT_TOT; idx+=stride){
    if(idx<ADJ_TOT) out[idx]=row[idx%MAXNN];
    else { int j=(idx-ADJ_TOT)&(HH-1); out[idx]=row[MAXNN+j]; }
  }
}

extern "C" void kernel_launch(void* const* d_in, const int* in_sizes, int n_in,
                              void* d_out, int out_size, void* d_ws, size_t ws_size,
                              hipStream_t stream){
  const float* x   = (const float*)d_in[0];
  const int*   ei  = (const int*)d_in[1];
  const float* ea  = (const float*)d_in[2];
  const float* eps = (const float*)d_in[3];
  const float* W1  =(const float*)d_in[5];
  const float* as1 =(const float*)d_in[6];
  const float* ad1 =(const float*)d_in[7];
  const float* We1 =(const float*)d_in[8];
  const float* ae1 =(const float*)d_in[9];
  const float* b1  =(const float*)d_in[10];
  const float* W2  =(const float*)d_in[11];
  const float* as2 =(const float*)d_in[12];
  const float* ad2 =(const float*)d_in[13];
  const float* We2 =(const float*)d_in[14];
  const float* ae2 =(const float*)d_in[15];
  const float* b2  =(const float*)d_in[16];
  const float* muW =(const float*)d_in[17];
  const float* mub =(const float*)d_in[18];
  const float* lvW =(const float*)d_in[19];
  const float* lvb =(const float*)d_in[20];
  const float* decW=(const float*)d_in[21];
  const float* decb=(const float*)d_in[22];
  const float* aW1 =(const float*)d_in[23];
  const float* ab1 =(const float*)d_in[24];
  const float* aW2 =(const float*)d_in[25];
  const float* ab2 =(const float*)d_in[26];
  const float* nW1 =(const float*)d_in[27];
  const float* nb1 =(const float*)d_in[28];
  const float* nW2 =(const float*)d_in[29];
  const float* nb2 =(const float*)d_in[30];
  float* out=(float*)d_out;

  char* w=(char*)d_ws;
  float* A        = (float*)w; w += (size_t)NN*HH*4;
  float* Bb       = (float*)w; w += (size_t)NN*HH*4;
  float* cet1     = (float*)w; w += (size_t)EF*4;
  float* cet2     = (float*)w; w += (size_t)EF*4;
  float* alphabuf = (float*)w; w += (size_t)EF*4;
  int*   csrc     = (int*)w;   w += (size_t)EF*4;
  int*   rowstart = (int*)w;   w += (size_t)(NN+1)*4;
  int*   fill     = (int*)w;   w += (size_t)NN*4;
  int*   ideg     = (int*)w;   w += (size_t)NN*4;
  float* etsum1   = (float*)w; w += (size_t)NN*4;
  float* etsum2   = (float*)w; w += (size_t)NN*4;
  float* asrc     = (float*)w; w += (size_t)NN*4;
  float* adst     = (float*)w; w += (size_t)NN*4;
  float* hgsum    = (float*)w; w += 128*4;
  float* wa1      = (float*)w; w += 16*4;
  float* wa2      = (float*)w; w += 16*4;
  float* rowadj   = (float*)w; w += 256*4;
  float* rownodes = (float*)w; w += 128*4;
  int*   blocksum = (int*)w;   w += 64*4;
  int*   blockoff = (int*)w;   w += 64*4;

  int nb = (NN+1023)/1024; // 49
  int gemmblocks = (NN+127)/128; // 391

  hipLaunchKernelGGL(kinit, dim3((NN+255)/256), dim3(256), 0, stream, ideg, fill, etsum1, etsum2, hgsum);
  hipLaunchKernelGGL(kwa, dim3(1), dim3(64), 0, stream, We1, ae1, We2, ae2, wa1, wa2);
  hipLaunchKernelGGL(kdeg, dim3((EE+255)/256), dim3(256), 0, stream, ei, ideg);
  hipLaunchKernelGGL(kscan1, dim3(nb), dim3(1024), 0, stream, ideg, rowstart, blocksum);
  hipLaunchKernelGGL(kscan2, dim3(1), dim3(64), 0, stream, blocksum, blockoff, nb);
  hipLaunchKernelGGL(kscan3, dim3((NN+255)/256), dim3(256), 0, stream, rowstart, blockoff, nb);
  hipLaunchKernelGGL(kscatter, dim3((EE+255)/256), dim3(256), 0, stream,
                     ei, ea, wa1, wa2, rowstart, fill, csrc, cet1, cet2, etsum1, etsum2);
  hipLaunchKernelGGL(kself, dim3((NN+255)/256), dim3(256), 0, stream,
                     rowstart, ideg, csrc, cet1, cet2, etsum1, etsum2);
  // layer 1
  hipLaunchKernelGGL(kgemm2, dim3(gemmblocks), dim3(256), 0, stream, x,  W1, as1, ad1, A, asrc, adst);
  hipLaunchKernelGGL(kgat,  dim3(NN), dim3(128), 0, stream, A, asrc, adst, rowstart, csrc, cet1, b1, alphabuf, Bb);
  // layer 2
  hipLaunchKernelGGL(kgemm2, dim3(gemmblocks), dim3(256), 0, stream, Bb, W2, as2, ad2, A, asrc, adst);
  hipLaunchKernelGGL(kgat,  dim3(NN), dim3(128), 0, stream, A, asrc, adst, rowstart, csrc, cet2, b2, alphabuf, Bb);
  // graph embedding + decoder + broadcast
  hipLaunchKernelGGL(khg,   dim3(256), dim3(128), 0, stream, Bb, hgsum);
  hipLaunchKernelGGL(kdec,  dim3(1), dim3(256), 0, stream, hgsum, eps,
                     muW,mub,lvW,lvb,decW,decb,aW1,ab1,aW2,ab2,nW1,nb1,nW2,nb2,
                     out, rowadj, rownodes);
  hipLaunchKernelGGL(kbcast, dim3(2048), dim3(256), 0, stream, rowadj, rownodes, out);
}

// Round 3
// 618.944 us; speedup vs baseline: 1.2992x; 1.0721x over previous
//
#include <hip/hip_runtime.h>
#include <math.h>

#define NN   50000
#define EE   800000
#define EF   850000   // EE + NN self loops
#define HH   128
#define FE   16
#define LATD 64
#define MAXNN 200

#define ADJ_TOT   10000000   // NN*MAXNN
#define NODES_TOT 6400000    // NN*HH
#define OUT_TOT   16400000   // ADJ_TOT + NODES_TOT
#define MU_OFF    16400000
#define LV_OFF    16400064

// ---------------- init ----------------
__global__ void kinit(int* ideg, int* fill, float* hgsum){
  int i = blockIdx.x*blockDim.x + threadIdx.x;
  if(i < NN){ ideg[i]=0; fill[i]=0; }
  if(i < HH) hgsum[i]=0.f;
}

// wa[f] = sum_j We[f][j]*att_e[j]   (fold edge-MLP into 16-vector)
__global__ void kwa(const float* We1, const float* ae1, const float* We2, const float* ae2,
                    float* wa1, float* wa2){
  int t = threadIdx.x;
  if(t < FE){
    float s1=0.f, s2=0.f;
    for(int j=0;j<HH;j++){ s1 += We1[t*HH+j]*ae1[j]; s2 += We2[t*HH+j]*ae2[j]; }
    wa1[t]=s1; wa2[t]=s2;
  }
}

__global__ void kdeg(const int* __restrict__ ei, int* ideg){
  int e = blockIdx.x*blockDim.x + threadIdx.x;
  if(e<EE) atomicAdd(&ideg[ei[EE+e]], 1);
}

// ---------------- exclusive scan of rowlen = ideg+1 ----------------
__global__ void kscan1(const int* __restrict__ ideg, int* rowstart, int* blocksum){
  __shared__ int sd[1024];
  int t=threadIdx.x; int i=blockIdx.x*1024+t;
  int v = (i<NN)? (ideg[i]+1) : 0;
  sd[t]=v; __syncthreads();
  for(int off=1; off<1024; off<<=1){
    int x = (t>=off)? sd[t-off] : 0;
    __syncthreads();
    sd[t] += x;
    __syncthreads();
  }
  if(i<NN) rowstart[i] = sd[t]-v;
  if(t==1023) blocksum[blockIdx.x]=sd[1023];
}
__global__ void kscan2(const int* blocksum, int* blockoff, int nb){
  if(threadIdx.x==0){
    int run=0;
    for(int b=0;b<nb;b++){ blockoff[b]=run; run+=blocksum[b]; }
    blockoff[nb]=run;
  }
}
__global__ void kscan3(int* rowstart, const int* __restrict__ blockoff, int nb){
  int i=blockIdx.x*blockDim.x+threadIdx.x;
  if(i<NN) rowstart[i]+=blockoff[i>>10];
  if(i==0) rowstart[NN]=blockoff[nb];
}

// ---------------- CSR scatter: one packed 16B entry per edge ----------------
// entry = {src (int bits), et1, et2, pad}
__global__ void kscatter(const int* __restrict__ ei, const float* __restrict__ ea,
                         const float* __restrict__ wa1, const float* __restrict__ wa2,
                         const int* __restrict__ rowstart, int* fill,
                         float4* __restrict__ csr){
  int e=blockIdx.x*blockDim.x+threadIdx.x;
  if(e>=EE) return;
  int s=ei[e], d=ei[EE+e];
  const float4* ea4 = (const float4*)(ea + (size_t)e*FE);
  float4 v0=ea4[0], v1=ea4[1], v2=ea4[2], v3=ea4[3];
  float va[16]={v0.x,v0.y,v0.z,v0.w, v1.x,v1.y,v1.z,v1.w,
                v2.x,v2.y,v2.z,v2.w, v3.x,v3.y,v3.z,v3.w};
  float d1=0.f,d2=0.f;
  #pragma unroll
  for(int f=0;f<FE;f++){ d1+=va[f]*wa1[f]; d2+=va[f]*wa2[f]; }
  int pos = rowstart[d] + atomicAdd(&fill[d],1);
  csr[pos] = make_float4(__int_as_float(s), d1, d2, 0.f);
}

// self-loop entry: et = mean of row's et values; scans own row (contiguous)
__global__ void kself(const int* __restrict__ rowstart, const int* __restrict__ ideg,
                      float4* __restrict__ csr){
  int i=blockIdx.x*blockDim.x+threadIdx.x;
  if(i>=NN) return;
  int base = rowstart[i]; int deg = ideg[i];
  float s1=0.f, s2=0.f;
  for(int k=0;k<deg;k++){ float4 en=csr[base+k]; s1+=en.y; s2+=en.z; }
  float dg = (float)deg; if(dg<1.f) dg=1.f;
  csr[base+deg] = make_float4(__int_as_float(i), s1/dg, s2/dg, 0.f);
}

// ---------------- tiled fp32 GEMM: G = h @ W, plus asrc/adst row dots ----------------
// block: 256 threads; tile: 128 rows x 128 cols; thread micro-tile 8x8.
// h tile staged in LDS (64 KB) with XOR swizzle on k-quads -> conflict-free b128.
__global__ __launch_bounds__(256) void kgemm2(const float* __restrict__ hin,
    const float* __restrict__ W,
    const float* __restrict__ atts, const float* __restrict__ attd,
    float* __restrict__ G, float* __restrict__ asrc, float* __restrict__ adst){
  __shared__ float hs[128*128];   // 64 KB, stride 128 dwords, swizzled
  int t = threadIdx.x;
  int row0 = blockIdx.x * 128;
  #pragma unroll
  for(int it=0; it<16; ++it){
    int f = it*256 + t;          // float4 index 0..4095
    int r = f >> 5;              // 32 float4-chunks per row
    int c4 = f & 31;
    int grow = row0 + r;
    float4 v = make_float4(0.f,0.f,0.f,0.f);
    if(grow < NN) v = *(const float4*)(hin + (size_t)grow*HH + c4*4);
    int sc4 = c4 ^ ((r>>3)&3);
    *(float4*)(hs + r*HH + sc4*4) = v;
  }
  __syncthreads();

  int tcg = t & 15;              // col group: cols c0..c0+7
  int trg = t >> 4;              // row group: rows r0..r0+7
  int c0  = tcg*8;
  int r0  = trg*8;
  int sw  = trg & 3;             // read-side swizzle

  float s_att[8], d_att[8];
  #pragma unroll
  for(int c=0;c<8;c++){ s_att[c]=atts[c0+c]; d_att[c]=attd[c0+c]; }

  float acc[8][8];
  #pragma unroll
  for(int r=0;r<8;r++)
    #pragma unroll
    for(int c=0;c<8;c++) acc[r][c]=0.f;

  for(int k=0;k<HH;k+=4){
    int k4 = k>>2;
    float4 hv[8];
    #pragma unroll
    for(int r=0;r<8;r++)
      hv[r] = *(const float4*)(hs + (r0+r)*HH + ((k4 ^ sw)<<2));
    #pragma unroll
    for(int kk=0;kk<4;kk++){
      float4 w0 = *(const float4*)(W + (size_t)(k+kk)*HH + c0);
      float4 w1 = *(const float4*)(W + (size_t)(k+kk)*HH + c0 + 4);
      float wz[8] = {w0.x,w0.y,w0.z,w0.w,w1.x,w1.y,w1.z,w1.w};
      #pragma unroll
      for(int r=0;r<8;r++){
        float hval = (kk==0)?hv[r].x : (kk==1)?hv[r].y : (kk==2)?hv[r].z : hv[r].w;
        #pragma unroll
        for(int c=0;c<8;c++) acc[r][c] += hval * wz[c];
      }
    }
  }

  #pragma unroll
  for(int r=0;r<8;r++){
    int grow = row0 + r0 + r;
    float ps=0.f, pd=0.f;
    #pragma unroll
    for(int c=0;c<8;c++){ ps += acc[r][c]*s_att[c]; pd += acc[r][c]*d_att[c]; }
    #pragma unroll
    for(int m=8;m>=1;m>>=1){ ps += __shfl_xor(ps,m,16); pd += __shfl_xor(pd,m,16); }
    if(grow < NN){
      float4 o0 = make_float4(acc[r][0],acc[r][1],acc[r][2],acc[r][3]);
      float4 o1 = make_float4(acc[r][4],acc[r][5],acc[r][6],acc[r][7]);
      *(float4*)(G + (size_t)grow*HH + c0)     = o0;
      *(float4*)(G + (size_t)grow*HH + c0 + 4) = o1;
      if(tcg==0){ asrc[grow]=ps; adst[grow]=pd; }
    }
  }
}

// ---------------- GAT softmax-aggregate, one block per dst node ----------------
// etsel: 0 -> entry.y (layer1), 1 -> entry.z (layer2)
__global__ __launch_bounds__(128) void kgat(const float* __restrict__ A,
    const float* __restrict__ asrc, const float* __restrict__ adst,
    const int* __restrict__ rowstart, const float4* __restrict__ csr,
    int etsel, const float* __restrict__ bias,
    float* __restrict__ alphabuf, int* __restrict__ srcbuf,
    float* __restrict__ Bout){
  int i = blockIdx.x; int t = threadIdx.x;
  int base = rowstart[i]; int len = rowstart[i+1]-base;
  __shared__ float red[HH];
  __shared__ float sal[1024];
  __shared__ int   ssrc[1024];
  bool inlds = (len <= 1024);
  float adi = adst[i];
  // phase 1: alpha + row max (one 16B read per edge)
  float lmax = -1e30f;
  for(int k=t;k<len;k+=HH){
    float4 en = csr[base+k];
    int s = __float_as_int(en.x);
    float et = etsel ? en.z : en.y;
    float a = asrc[s] + adi + et;
    a = a>0.f ? a : 0.2f*a;            // leaky_relu 0.2
    if(inlds){ sal[k]=a; ssrc[k]=s; }
    else { alphabuf[base+k]=a; srcbuf[base+k]=s; }
    lmax = fmaxf(lmax,a);
  }
  red[t]=lmax; __syncthreads();
  for(int off=64;off>0;off>>=1){ if(t<off) red[t]=fmaxf(red[t],red[t+off]); __syncthreads(); }
  float m = red[0];
  __syncthreads();
  // phase 2: exp + sum
  float lsum=0.f;
  for(int k=t;k<len;k+=HH){
    float a = inlds ? sal[k] : alphabuf[base+k];
    float ex = __expf(a-m);
    if(inlds) sal[k]=ex; else alphabuf[base+k]=ex;
    lsum += ex;
  }
  red[t]=lsum; __syncthreads();
  for(int off=64;off>0;off>>=1){ if(t<off) red[t]+=red[t+off]; __syncthreads(); }
  float den = red[0];
  __syncthreads();
  // phase 3: weighted gather of g[src] rows (coalesced 512B per edge)
  float acc=0.f;
  for(int k=0;k<len;k++){
    float wgt = inlds ? sal[k] : alphabuf[base+k];
    int s = inlds ? ssrc[k] : srcbuf[base+k];
    acc += wgt * A[(size_t)s*HH+t];
  }
  Bout[(size_t)i*HH+t] = fmaxf(acc/den + bias[t], 0.f);
}

// ---------------- column mean partials ----------------
__global__ __launch_bounds__(128) void khg(const float* __restrict__ B, float* hgsum){
  int f=threadIdx.x; int b=blockIdx.x; int nb=gridDim.x;
  int chunk=(NN+nb-1)/nb;
  int i0=b*chunk, i1=min(i0+chunk, NN);
  float s=0.f;
  for(int i=i0;i<i1;i++) s += B[(size_t)i*HH+f];
  atomicAdd(&hgsum[f], s);
}

// ---------------- tiny decoder, single block ----------------
__global__ __launch_bounds__(256) void kdec(const float* __restrict__ hgsum, const float* __restrict__ eps,
   const float* muW,const float* mub,const float* lvW,const float* lvb,
   const float* decW,const float* decb,
   const float* aW1,const float* ab1,const float* aW2,const float* ab2,
   const float* nW1,const float* nb1,const float* nW2,const float* nb2,
   float* out, float* rowadj, float* rownodes){
  __shared__ float hg[HH], z[LATD], hd[HH], t1[HH], t2[HH];
  int t=threadIdx.x;
  if(t<HH) hg[t]=hgsum[t]*(1.0f/NN);
  __syncthreads();
  if(t<LATD){
    float mu=mub[t], lv=lvb[t];
    for(int k=0;k<HH;k++){ mu += hg[k]*muW[k*LATD+t]; lv += hg[k]*lvW[k*LATD+t]; }
    out[MU_OFF+t]=mu; out[LV_OFF+t]=lv;
    z[t]=mu + eps[t]*expf(0.5f*lv);
  }
  __syncthreads();
  if(t<HH){
    float a=decb[t];
    for(int k=0;k<LATD;k++) a += z[k]*decW[k*HH+t];
    hd[t]=fmaxf(a,0.f);
  }
  __syncthreads();
  if(t<HH){
    float a=ab1[t];
    for(int k=0;k<HH;k++) a += hd[k]*aW1[k*HH+t];
    t1[t]=fmaxf(a,0.f);
  } else {
    int j=t-HH;
    float a=nb1[j];
    for(int k=0;k<HH;k++) a += hd[k]*nW1[k*HH+j];
    t2[j]=fmaxf(a,0.f);
  }
  __syncthreads();
  for(int j=t;j<MAXNN;j+=256){
    float a=ab2[j];
    for(int k=0;k<HH;k++) a += t1[k]*aW2[k*MAXNN+j];
    rowadj[j]=a;
  }
  if(t<HH){
    float a=nb2[t];
    for(int k=0;k<HH;k++) a += t2[k]*nW2[k*HH+t];
    rownodes[t]=a;
  }
}

// ---------------- broadcast the two decoder rows over all N nodes ----------------
__global__ __launch_bounds__(256) void kbcast(const float* __restrict__ rowadj,
                                              const float* __restrict__ rownodes,
                                              float* __restrict__ out){
  __shared__ float row[MAXNN+HH];
  int t=threadIdx.x;
  if(t<MAXNN) row[t]=rowadj[t];
  if(t<HH) row[MAXNN+t]=rownodes[t];
  __syncthreads();
  int stride=gridDim.x*blockDim.x;
  for(int idx=blockIdx.x*blockDim.x+t; idx<OUT_TOT; idx+=stride){
    if(idx<ADJ_TOT) out[idx]=row[idx%MAXNN];
    else { int j=(idx-ADJ_TOT)&(HH-1); out[idx]=row[MAXNN+j]; }
  }
}

extern "C" void kernel_launch(void* const* d_in, const int* in_sizes, int n_in,
                              void* d_out, int out_size, void* d_ws, size_t ws_size,
                              hipStream_t stream){
  const float* x   = (const float*)d_in[0];
  const int*   ei  = (const int*)d_in[1];
  const float* ea  = (const float*)d_in[2];
  const float* eps = (const float*)d_in[3];
  const float* W1  =(const float*)d_in[5];
  const float* as1 =(const float*)d_in[6];
  const float* ad1 =(const float*)d_in[7];
  const float* We1 =(const float*)d_in[8];
  const float* ae1 =(const float*)d_in[9];
  const float* b1  =(const float*)d_in[10];
  const float* W2  =(const float*)d_in[11];
  const float* as2 =(const float*)d_in[12];
  const float* ad2 =(const float*)d_in[13];
  const float* We2 =(const float*)d_in[14];
  const float* ae2 =(const float*)d_in[15];
  const float* b2  =(const float*)d_in[16];
  const float* muW =(const float*)d_in[17];
  const float* mub =(const float*)d_in[18];
  const float* lvW =(const float*)d_in[19];
  const float* lvb =(const float*)d_in[20];
  const float* decW=(const float*)d_in[21];
  const float* decb=(const float*)d_in[22];
  const float* aW1 =(const float*)d_in[23];
  const float* ab1 =(const float*)d_in[24];
  const float* aW2 =(const float*)d_in[25];
  const float* ab2 =(const float*)d_in[26];
  const float* nW1 =(const float*)d_in[27];
  const float* nb1 =(const float*)d_in[28];
  const float* nW2 =(const float*)d_in[29];
  const float* nb2 =(const float*)d_in[30];
  float* out=(float*)d_out;

  char* w=(char*)d_ws;
  float*  A        = (float*)w;  w += (size_t)NN*HH*4;
  float*  Bb       = (float*)w;  w += (size_t)NN*HH*4;
  float4* csr      = (float4*)w; w += (size_t)EF*16;
  float*  alphabuf = (float*)w;  w += (size_t)EF*4;
  int*    srcbuf   = (int*)w;    w += (size_t)EF*4;
  int*    rowstart = (int*)w;    w += (size_t)(NN+1)*4;
  int*    fill     = (int*)w;    w += (size_t)NN*4;
  int*    ideg     = (int*)w;    w += (size_t)NN*4;
  float*  asrc     = (float*)w;  w += (size_t)NN*4;
  float*  adst     = (float*)w;  w += (size_t)NN*4;
  float*  hgsum    = (float*)w;  w += 128*4;
  float*  wa1      = (float*)w;  w += 16*4;
  float*  wa2      = (float*)w;  w += 16*4;
  float*  rowadj   = (float*)w;  w += 256*4;
  float*  rownodes = (float*)w;  w += 128*4;
  int*    blocksum = (int*)w;    w += 64*4;
  int*    blockoff = (int*)w;    w += 64*4;

  int nb = (NN+1023)/1024; // 49
  int gemmblocks = (NN+127)/128; // 391

  hipLaunchKernelGGL(kinit, dim3((NN+255)/256), dim3(256), 0, stream, ideg, fill, hgsum);
  hipLaunchKernelGGL(kwa, dim3(1), dim3(64), 0, stream, We1, ae1, We2, ae2, wa1, wa2);
  hipLaunchKernelGGL(kdeg, dim3((EE+255)/256), dim3(256), 0, stream, ei, ideg);
  hipLaunchKernelGGL(kscan1, dim3(nb), dim3(1024), 0, stream, ideg, rowstart, blocksum);
  hipLaunchKernelGGL(kscan2, dim3(1), dim3(64), 0, stream, blocksum, blockoff, nb);
  hipLaunchKernelGGL(kscan3, dim3((NN+255)/256), dim3(256), 0, stream, rowstart, blockoff, nb);
  hipLaunchKernelGGL(kscatter, dim3((EE+255)/256), dim3(256), 0, stream,
                     ei, ea, wa1, wa2, rowstart, fill, csr);
  hipLaunchKernelGGL(kself, dim3((NN+255)/256), dim3(256), 0, stream, rowstart, ideg, csr);
  // layer 1
  hipLaunchKernelGGL(kgemm2, dim3(gemmblocks), dim3(256), 0, stream, x,  W1, as1, ad1, A, asrc, adst);
  hipLaunchKernelGGL(kgat,  dim3(NN), dim3(128), 0, stream, A, asrc, adst, rowstart, csr, 0, b1, alphabuf, srcbuf, Bb);
  // layer 2
  hipLaunchKernelGGL(kgemm2, dim3(gemmblocks), dim3(256), 0, stream, Bb, W2, as2, ad2, A, asrc, adst);
  hipLaunchKernelGGL(kgat,  dim3(NN), dim3(128), 0, stream, A, asrc, adst, rowstart, csr, 1, b2, alphabuf, srcbuf, Bb);
  // graph embedding + decoder + broadcast
  hipLaunchKernelGGL(khg,   dim3(256), dim3(128), 0, stream, Bb, hgsum);
  hipLaunchKernelGGL(kdec,  dim3(1), dim3(256), 0, stream, hgsum, eps,
                     muW,mub,lvW,lvb,decW,decb,aW1,ab1,aW2,ab2,nW1,nb1,nW2,nb2,
                     out, rowadj, rownodes);
  hipLaunchKernelGGL(kbcast, dim3(2048), dim3(256), 0, stream, rowadj, rownodes, out);
}

// Round 4
// 611.269 us; speedup vs baseline: 1.3155x; 1.0126x over previous
//
#include <hip/hip_runtime.h>
#include <math.h>

#define NN   50000
#define EE   800000
#define EF   850000   // EE + NN self loops
#define HH   128
#define FE   16
#define LATD 64
#define MAXNN 200

#define ADJ_TOT   10000000   // NN*MAXNN
#define NODES_TOT 6400000    // NN*HH
#define OUT_TOT   16400000   // ADJ_TOT + NODES_TOT
#define MU_OFF    16400000
#define LV_OFF    16400064

__device__ __forceinline__ unsigned short f2bf(float f){
  unsigned int u = __float_as_uint(f);
  unsigned int r = (u + 0x7FFFu + ((u>>16)&1u)) >> 16;   // RNE
  return (unsigned short)r;
}
__device__ __forceinline__ float bf2f(unsigned short h){
  return __uint_as_float(((unsigned int)h)<<16);
}

// ---------------- init ----------------
__global__ void kinit(int* ideg, int* fill, float* hgsum){
  int i = blockIdx.x*blockDim.x + threadIdx.x;
  if(i < NN){ ideg[i]=0; fill[i]=0; }
  if(i < HH) hgsum[i]=0.f;
}

// wa[f] = sum_j We[f][j]*att_e[j]   (fold edge-MLP into 16-vector)
__global__ void kwa(const float* We1, const float* ae1, const float* We2, const float* ae2,
                    float* wa1, float* wa2){
  int t = threadIdx.x;
  if(t < FE){
    float s1=0.f, s2=0.f;
    for(int j=0;j<HH;j++){ s1 += We1[t*HH+j]*ae1[j]; s2 += We2[t*HH+j]*ae2[j]; }
    wa1[t]=s1; wa2[t]=s2;
  }
}

__global__ void kdeg(const int* __restrict__ ei, int* ideg){
  int e = blockIdx.x*blockDim.x + threadIdx.x;
  if(e<EE) atomicAdd(&ideg[ei[EE+e]], 1);
}

// ---------------- exclusive scan of rowlen = ideg+1 ----------------
__global__ void kscan1(const int* __restrict__ ideg, int* rowstart, int* blocksum){
  __shared__ int sd[1024];
  int t=threadIdx.x; int i=blockIdx.x*1024+t;
  int v = (i<NN)? (ideg[i]+1) : 0;
  sd[t]=v; __syncthreads();
  for(int off=1; off<1024; off<<=1){
    int x = (t>=off)? sd[t-off] : 0;
    __syncthreads();
    sd[t] += x;
    __syncthreads();
  }
  if(i<NN) rowstart[i] = sd[t]-v;
  if(t==1023) blocksum[blockIdx.x]=sd[1023];
}
__global__ void kscan2(const int* blocksum, int* blockoff, int nb){
  if(threadIdx.x==0){
    int run=0;
    for(int b=0;b<nb;b++){ blockoff[b]=run; run+=blocksum[b]; }
    blockoff[nb]=run;
  }
}
__global__ void kscan3(int* rowstart, const int* __restrict__ blockoff, int nb){
  int i=blockIdx.x*blockDim.x+threadIdx.x;
  if(i<NN) rowstart[i]+=blockoff[i>>10];
  if(i==0) rowstart[NN]=blockoff[nb];
}

// ---------------- CSR scatter: one packed 16B entry per edge ----------------
// entry = {src (int bits), et1, et2, pad}
__global__ void kscatter(const int* __restrict__ ei, const float* __restrict__ ea,
                         const float* __restrict__ wa1, const float* __restrict__ wa2,
                         const int* __restrict__ rowstart, int* fill,
                         float4* __restrict__ csr){
  int e=blockIdx.x*blockDim.x+threadIdx.x;
  if(e>=EE) return;
  int s=ei[e], d=ei[EE+e];
  const float4* ea4 = (const float4*)(ea + (size_t)e*FE);
  float4 v0=ea4[0], v1=ea4[1], v2=ea4[2], v3=ea4[3];
  float va[16]={v0.x,v0.y,v0.z,v0.w, v1.x,v1.y,v1.z,v1.w,
                v2.x,v2.y,v2.z,v2.w, v3.x,v3.y,v3.z,v3.w};
  float d1=0.f,d2=0.f;
  #pragma unroll
  for(int f=0;f<FE;f++){ d1+=va[f]*wa1[f]; d2+=va[f]*wa2[f]; }
  int pos = rowstart[d] + atomicAdd(&fill[d],1);
  csr[pos] = make_float4(__int_as_float(s), d1, d2, 0.f);
}

// self-loop entry: et = mean of row's et values; scans own row (contiguous)
__global__ void kself(const int* __restrict__ rowstart, const int* __restrict__ ideg,
                      float4* __restrict__ csr){
  int i=blockIdx.x*blockDim.x+threadIdx.x;
  if(i>=NN) return;
  int base = rowstart[i]; int deg = ideg[i];
  float s1=0.f, s2=0.f;
  for(int k=0;k<deg;k++){ float4 en=csr[base+k]; s1+=en.y; s2+=en.z; }
  float dg = (float)deg; if(dg<1.f) dg=1.f;
  csr[base+deg] = make_float4(__int_as_float(i), s1/dg, s2/dg, 0.f);
}

// ---------------- tiled fp32 GEMM: Gbf = bf16(h @ W), plus asrc/adst row dots ----------------
// block: 256 threads; tile: 128 rows x 128 cols; thread micro-tile 8x8.
// h tile staged in LDS (64 KB) with XOR swizzle on k-quads -> conflict-free b128.
__global__ __launch_bounds__(256) void kgemm2(const float* __restrict__ hin,
    const float* __restrict__ W,
    const float* __restrict__ atts, const float* __restrict__ attd,
    unsigned short* __restrict__ Gbf, float* __restrict__ asrc, float* __restrict__ adst){
  __shared__ float hs[128*128];   // 64 KB, stride 128 dwords, swizzled
  int t = threadIdx.x;
  int row0 = blockIdx.x * 128;
  #pragma unroll
  for(int it=0; it<16; ++it){
    int f = it*256 + t;          // float4 index 0..4095
    int r = f >> 5;              // 32 float4-chunks per row
    int c4 = f & 31;
    int grow = row0 + r;
    float4 v = make_float4(0.f,0.f,0.f,0.f);
    if(grow < NN) v = *(const float4*)(hin + (size_t)grow*HH + c4*4);
    int sc4 = c4 ^ ((r>>3)&3);
    *(float4*)(hs + r*HH + sc4*4) = v;
  }
  __syncthreads();

  int tcg = t & 15;              // col group: cols c0..c0+7
  int trg = t >> 4;              // row group: rows r0..r0+7
  int c0  = tcg*8;
  int r0  = trg*8;
  int sw  = trg & 3;             // read-side swizzle

  float s_att[8], d_att[8];
  #pragma unroll
  for(int c=0;c<8;c++){ s_att[c]=atts[c0+c]; d_att[c]=attd[c0+c]; }

  float acc[8][8];
  #pragma unroll
  for(int r=0;r<8;r++)
    #pragma unroll
    for(int c=0;c<8;c++) acc[r][c]=0.f;

  for(int k=0;k<HH;k+=4){
    int k4 = k>>2;
    float4 hv[8];
    #pragma unroll
    for(int r=0;r<8;r++)
      hv[r] = *(const float4*)(hs + (r0+r)*HH + ((k4 ^ sw)<<2));
    #pragma unroll
    for(int kk=0;kk<4;kk++){
      float4 w0 = *(const float4*)(W + (size_t)(k+kk)*HH + c0);
      float4 w1 = *(const float4*)(W + (size_t)(k+kk)*HH + c0 + 4);
      float wz[8] = {w0.x,w0.y,w0.z,w0.w,w1.x,w1.y,w1.z,w1.w};
      #pragma unroll
      for(int r=0;r<8;r++){
        float hval = (kk==0)?hv[r].x : (kk==1)?hv[r].y : (kk==2)?hv[r].z : hv[r].w;
        #pragma unroll
        for(int c=0;c<8;c++) acc[r][c] += hval * wz[c];
      }
    }
  }

  #pragma unroll
  for(int r=0;r<8;r++){
    int grow = row0 + r0 + r;
    float ps=0.f, pd=0.f;
    #pragma unroll
    for(int c=0;c<8;c++){ ps += acc[r][c]*s_att[c]; pd += acc[r][c]*d_att[c]; }
    #pragma unroll
    for(int m=8;m>=1;m>>=1){ ps += __shfl_xor(ps,m,16); pd += __shfl_xor(pd,m,16); }
    if(grow < NN){
      uint4 o;
      o.x = (unsigned)f2bf(acc[r][0]) | ((unsigned)f2bf(acc[r][1])<<16);
      o.y = (unsigned)f2bf(acc[r][2]) | ((unsigned)f2bf(acc[r][3])<<16);
      o.z = (unsigned)f2bf(acc[r][4]) | ((unsigned)f2bf(acc[r][5])<<16);
      o.w = (unsigned)f2bf(acc[r][6]) | ((unsigned)f2bf(acc[r][7])<<16);
      *(uint4*)(Gbf + (size_t)grow*HH + c0) = o;   // 16B aligned (c0 mult of 8)
      if(tcg==0){ asrc[grow]=ps; adst[grow]=pd; }
    }
  }
}

// ---------------- GAT softmax-aggregate, one block per dst node ----------------
// etsel: 0 -> entry.y (layer1), 1 -> entry.z (layer2)
__global__ __launch_bounds__(128) void kgat(const unsigned short* __restrict__ A,
    const float* __restrict__ asrc, const float* __restrict__ adst,
    const int* __restrict__ rowstart, const float4* __restrict__ csr,
    int etsel, const float* __restrict__ bias,
    float* __restrict__ alphabuf, int* __restrict__ srcbuf,
    float* __restrict__ Bout){
  int i = blockIdx.x; int t = threadIdx.x;
  int base = rowstart[i]; int len = rowstart[i+1]-base;
  __shared__ float red[HH];
  __shared__ float sal[1024];
  __shared__ int   ssrc[1024];
  bool inlds = (len <= 1024);
  float adi = adst[i];
  // phase 1: alpha + row max (one 16B read per edge)
  float lmax = -1e30f;
  for(int k=t;k<len;k+=HH){
    float4 en = csr[base+k];
    int s = __float_as_int(en.x);
    float et = etsel ? en.z : en.y;
    float a = asrc[s] + adi + et;
    a = a>0.f ? a : 0.2f*a;            // leaky_relu 0.2
    if(inlds){ sal[k]=a; ssrc[k]=s; }
    else { alphabuf[base+k]=a; srcbuf[base+k]=s; }
    lmax = fmaxf(lmax,a);
  }
  red[t]=lmax; __syncthreads();
  for(int off=64;off>0;off>>=1){ if(t<off) red[t]=fmaxf(red[t],red[t+off]); __syncthreads(); }
  float m = red[0];
  __syncthreads();
  // phase 2: exp + sum
  float lsum=0.f;
  for(int k=t;k<len;k+=HH){
    float a = inlds ? sal[k] : alphabuf[base+k];
    float ex = __expf(a-m);
    if(inlds) sal[k]=ex; else alphabuf[base+k]=ex;
    lsum += ex;
  }
  red[t]=lsum; __syncthreads();
  for(int off=64;off>0;off>>=1){ if(t<off) red[t]+=red[t+off]; __syncthreads(); }
  float den = red[0];
  __syncthreads();
  // phase 3: weighted gather of bf16 g[src] rows (256B per edge, coalesced)
  float acc=0.f;
  for(int k=0;k<len;k++){
    float wgt = inlds ? sal[k] : alphabuf[base+k];
    int s = inlds ? ssrc[k] : srcbuf[base+k];
    acc += wgt * bf2f(A[(size_t)s*HH+t]);
  }
  Bout[(size_t)i*HH+t] = fmaxf(acc/den + bias[t], 0.f);
}

// ---------------- column mean partials ----------------
__global__ __launch_bounds__(128) void khg(const float* __restrict__ B, float* hgsum){
  int f=threadIdx.x; int b=blockIdx.x; int nb=gridDim.x;
  int chunk=(NN+nb-1)/nb;
  int i0=b*chunk, i1=min(i0+chunk, NN);
  float s=0.f;
  for(int i=i0;i<i1;i++) s += B[(size_t)i*HH+f];
  atomicAdd(&hgsum[f], s);
}

// ---------------- tiny decoder, single block ----------------
__global__ __launch_bounds__(256) void kdec(const float* __restrict__ hgsum, const float* __restrict__ eps,
   const float* muW,const float* mub,const float* lvW,const float* lvb,
   const float* decW,const float* decb,
   const float* aW1,const float* ab1,const float* aW2,const float* ab2,
   const float* nW1,const float* nb1,const float* nW2,const float* nb2,
   float* out, float* rowadj, float* rownodes){
  __shared__ float hg[HH], z[LATD], hd[HH], t1[HH], t2[HH];
  int t=threadIdx.x;
  if(t<HH) hg[t]=hgsum[t]*(1.0f/NN);
  __syncthreads();
  if(t<LATD){
    float mu=mub[t], lv=lvb[t];
    for(int k=0;k<HH;k++){ mu += hg[k]*muW[k*LATD+t]; lv += hg[k]*lvW[k*LATD+t]; }
    out[MU_OFF+t]=mu; out[LV_OFF+t]=lv;
    z[t]=mu + eps[t]*expf(0.5f*lv);
  }
  __syncthreads();
  if(t<HH){
    float a=decb[t];
    for(int k=0;k<LATD;k++) a += z[k]*decW[k*HH+t];
    hd[t]=fmaxf(a,0.f);
  }
  __syncthreads();
  if(t<HH){
    float a=ab1[t];
    for(int k=0;k<HH;k++) a += hd[k]*aW1[k*HH+t];
    t1[t]=fmaxf(a,0.f);
  } else {
    int j=t-HH;
    float a=nb1[j];
    for(int k=0;k<HH;k++) a += hd[k]*nW1[k*HH+j];
    t2[j]=fmaxf(a,0.f);
  }
  __syncthreads();
  for(int j=t;j<MAXNN;j+=256){
    float a=ab2[j];
    for(int k=0;k<HH;k++) a += t1[k]*aW2[k*MAXNN+j];
    rowadj[j]=a;
  }
  if(t<HH){
    float a=nb2[t];
    for(int k=0;k<HH;k++) a += t2[k]*nW2[k*HH+t];
    rownodes[t]=a;
  }
}

// ---------------- broadcast the two decoder rows over all N nodes ----------------
__global__ __launch_bounds__(256) void kbcast(const float* __restrict__ rowadj,
                                              const float* __restrict__ rownodes,
                                              float* __restrict__ out){
  __shared__ float row[MAXNN+HH];
  int t=threadIdx.x;
  if(t<MAXNN) row[t]=rowadj[t];
  if(t<HH) row[MAXNN+t]=rownodes[t];
  __syncthreads();
  int stride=gridDim.x*blockDim.x;
  for(int idx=blockIdx.x*blockDim.x+t; idx<OUT_TOT; idx+=stride){
    if(idx<ADJ_TOT) out[idx]=row[idx%MAXNN];
    else { int j=(idx-ADJ_TOT)&(HH-1); out[idx]=row[MAXNN+j]; }
  }
}

extern "C" void kernel_launch(void* const* d_in, const int* in_sizes, int n_in,
                              void* d_out, int out_size, void* d_ws, size_t ws_size,
                              hipStream_t stream){
  const float* x   = (const float*)d_in[0];
  const int*   ei  = (const int*)d_in[1];
  const float* ea  = (const float*)d_in[2];
  const float* eps = (const float*)d_in[3];
  const float* W1  =(const float*)d_in[5];
  const float* as1 =(const float*)d_in[6];
  const float* ad1 =(const float*)d_in[7];
  const float* We1 =(const float*)d_in[8];
  const float* ae1 =(const float*)d_in[9];
  const float* b1  =(const float*)d_in[10];
  const float* W2  =(const float*)d_in[11];
  const float* as2 =(const float*)d_in[12];
  const float* ad2 =(const float*)d_in[13];
  const float* We2 =(const float*)d_in[14];
  const float* ae2 =(const float*)d_in[15];
  const float* b2  =(const float*)d_in[16];
  const float* muW =(const float*)d_in[17];
  const float* mub =(const float*)d_in[18];
  const float* lvW =(const float*)d_in[19];
  const float* lvb =(const float*)d_in[20];
  const float* decW=(const float*)d_in[21];
  const float* decb=(const float*)d_in[22];
  const float* aW1 =(const float*)d_in[23];
  const float* ab1 =(const float*)d_in[24];
  const float* aW2 =(const float*)d_in[25];
  const float* ab2 =(const float*)d_in[26];
  const float* nW1 =(const float*)d_in[27];
  const float* nb1 =(const float*)d_in[28];
  const float* nW2 =(const float*)d_in[29];
  const float* nb2 =(const float*)d_in[30];
  float* out=(float*)d_out;

  char* w=(char*)d_ws;
  unsigned short* Abf = (unsigned short*)w; w += (size_t)NN*HH*2;
  float*  Bb       = (float*)w;  w += (size_t)NN*HH*4;
  float4* csr      = (float4*)w; w += (size_t)EF*16;
  float*  alphabuf = (float*)w;  w += (size_t)EF*4;
  int*    srcbuf   = (int*)w;    w += (size_t)EF*4;
  int*    rowstart = (int*)w;    w += (size_t)(NN+1)*4;
  int*    fill     = (int*)w;    w += (size_t)NN*4;
  int*    ideg     = (int*)w;    w += (size_t)NN*4;
  float*  asrc     = (float*)w;  w += (size_t)NN*4;
  float*  adst     = (float*)w;  w += (size_t)NN*4;
  float*  hgsum    = (float*)w;  w += 128*4;
  float*  wa1      = (float*)w;  w += 16*4;
  float*  wa2      = (float*)w;  w += 16*4;
  float*  rowadj   = (float*)w;  w += 256*4;
  float*  rownodes = (float*)w;  w += 128*4;
  int*    blocksum = (int*)w;    w += 64*4;
  int*    blockoff = (int*)w;    w += 64*4;

  int nb = (NN+1023)/1024; // 49
  int gemmblocks = (NN+127)/128; // 391

  hipLaunchKernelGGL(kinit, dim3((NN+255)/256), dim3(256), 0, stream, ideg, fill, hgsum);
  hipLaunchKernelGGL(kwa, dim3(1), dim3(64), 0, stream, We1, ae1, We2, ae2, wa1, wa2);
  hipLaunchKernelGGL(kdeg, dim3((EE+255)/256), dim3(256), 0, stream, ei, ideg);
  hipLaunchKernelGGL(kscan1, dim3(nb), dim3(1024), 0, stream, ideg, rowstart, blocksum);
  hipLaunchKernelGGL(kscan2, dim3(1), dim3(64), 0, stream, blocksum, blockoff, nb);
  hipLaunchKernelGGL(kscan3, dim3((NN+255)/256), dim3(256), 0, stream, rowstart, blockoff, nb);
  hipLaunchKernelGGL(kscatter, dim3((EE+255)/256), dim3(256), 0, stream,
                     ei, ea, wa1, wa2, rowstart, fill, csr);
  hipLaunchKernelGGL(kself, dim3((NN+255)/256), dim3(256), 0, stream, rowstart, ideg, csr);
  // layer 1
  hipLaunchKernelGGL(kgemm2, dim3(gemmblocks), dim3(256), 0, stream, x,  W1, as1, ad1, Abf, asrc, adst);
  hipLaunchKernelGGL(kgat,  dim3(NN), dim3(128), 0, stream, Abf, asrc, adst, rowstart, csr, 0, b1, alphabuf, srcbuf, Bb);
  // layer 2
  hipLaunchKernelGGL(kgemm2, dim3(gemmblocks), dim3(256), 0, stream, Bb, W2, as2, ad2, Abf, asrc, adst);
  hipLaunchKernelGGL(kgat,  dim3(NN), dim3(128), 0, stream, Abf, asrc, adst, rowstart, csr, 1, b2, alphabuf, srcbuf, Bb);
  // graph embedding + decoder + broadcast
  hipLaunchKernelGGL(khg,   dim3(256), dim3(128), 0, stream, Bb, hgsum);
  hipLaunchKernelGGL(kdec,  dim3(1), dim3(256), 0, stream, hgsum, eps,
                     muW,mub,lvW,lvb,decW,decb,aW1,ab1,aW2,ab2,nW1,nb1,nW2,nb2,
                     out, rowadj, rownodes);
  hipLaunchKernelGGL(kbcast, dim3(2048), dim3(256), 0, stream, rowadj, rownodes, out);
}

// Round 5
// 567.761 us; speedup vs baseline: 1.4163x; 1.0766x over previous
//
#include <hip/hip_runtime.h>
#include <math.h>

#define NN   50000
#define EE   800000
#define EF   850000   // EE + NN self loops
#define HH   128
#define FE   16
#define LATD 64
#define MAXNN 200

#define ADJ_TOT   10000000   // NN*MAXNN
#define NODES_TOT 6400000    // NN*HH
#define OUT_TOT   16400000   // ADJ_TOT + NODES_TOT
#define MU_OFF    16400000
#define LV_OFF    16400064

__device__ __forceinline__ unsigned short f2bf(float f){
  unsigned int u = __float_as_uint(f);
  unsigned int r = (u + 0x7FFFu + ((u>>16)&1u)) >> 16;   // RNE
  return (unsigned short)r;
}
__device__ __forceinline__ float bf2f(unsigned short h){
  return __uint_as_float(((unsigned int)h)<<16);
}

// ---------------- init ----------------
__global__ void kinit(int* ideg, int* fill, float* hgsum){
  int i = blockIdx.x*blockDim.x + threadIdx.x;
  if(i < NN){ ideg[i]=0; fill[i]=0; }
  if(i < HH) hgsum[i]=0.f;
}

// wa[f] = sum_j We[f][j]*att_e[j]   (fold edge-MLP into 16-vector)
__global__ void kwa(const float* We1, const float* ae1, const float* We2, const float* ae2,
                    float* wa1, float* wa2){
  int t = threadIdx.x;
  if(t < FE){
    float s1=0.f, s2=0.f;
    for(int j=0;j<HH;j++){ s1 += We1[t*HH+j]*ae1[j]; s2 += We2[t*HH+j]*ae2[j]; }
    wa1[t]=s1; wa2[t]=s2;
  }
}

__global__ void kdeg(const int* __restrict__ ei, int* ideg){
  int e = blockIdx.x*blockDim.x + threadIdx.x;
  if(e<EE) atomicAdd(&ideg[ei[EE+e]], 1);
}

// ---------------- exclusive scan of rowlen = ideg+1 ----------------
__global__ void kscan1(const int* __restrict__ ideg, int* rowstart, int* blocksum){
  __shared__ int sd[1024];
  int t=threadIdx.x; int i=blockIdx.x*1024+t;
  int v = (i<NN)? (ideg[i]+1) : 0;
  sd[t]=v; __syncthreads();
  for(int off=1; off<1024; off<<=1){
    int x = (t>=off)? sd[t-off] : 0;
    __syncthreads();
    sd[t] += x;
    __syncthreads();
  }
  if(i<NN) rowstart[i] = sd[t]-v;
  if(t==1023) blocksum[blockIdx.x]=sd[1023];
}
__global__ void kscan2(const int* blocksum, int* blockoff, int nb){
  if(threadIdx.x==0){
    int run=0;
    for(int b=0;b<nb;b++){ blockoff[b]=run; run+=blocksum[b]; }
    blockoff[nb]=run;
  }
}
__global__ void kscan3(int* rowstart, const int* __restrict__ blockoff, int nb){
  int i=blockIdx.x*blockDim.x+threadIdx.x;
  if(i<NN) rowstart[i]+=blockoff[i>>10];
  if(i==0) rowstart[NN]=blockoff[nb];
}

// ---------------- CSR scatter: one packed 16B entry per edge ----------------
// entry = {src (int bits), et1, et2, pad}
__global__ void kscatter(const int* __restrict__ ei, const float* __restrict__ ea,
                         const float* __restrict__ wa1, const float* __restrict__ wa2,
                         const int* __restrict__ rowstart, int* fill,
                         float4* __restrict__ csr){
  int e=blockIdx.x*blockDim.x+threadIdx.x;
  if(e>=EE) return;
  int s=ei[e], d=ei[EE+e];
  const float4* ea4 = (const float4*)(ea + (size_t)e*FE);
  float4 v0=ea4[0], v1=ea4[1], v2=ea4[2], v3=ea4[3];
  float va[16]={v0.x,v0.y,v0.z,v0.w, v1.x,v1.y,v1.z,v1.w,
                v2.x,v2.y,v2.z,v2.w, v3.x,v3.y,v3.z,v3.w};
  float d1=0.f,d2=0.f;
  #pragma unroll
  for(int f=0;f<FE;f++){ d1+=va[f]*wa1[f]; d2+=va[f]*wa2[f]; }
  int pos = rowstart[d] + atomicAdd(&fill[d],1);
  csr[pos] = make_float4(__int_as_float(s), d1, d2, 0.f);
}

// self-loop entry: et = mean of row's et values; scans own row (contiguous)
__global__ void kself(const int* __restrict__ rowstart, const int* __restrict__ ideg,
                      float4* __restrict__ csr){
  int i=blockIdx.x*blockDim.x+threadIdx.x;
  if(i>=NN) return;
  int base = rowstart[i]; int deg = ideg[i];
  float s1=0.f, s2=0.f;
  for(int k=0;k<deg;k++){ float4 en=csr[base+k]; s1+=en.y; s2+=en.z; }
  float dg = (float)deg; if(dg<1.f) dg=1.f;
  csr[base+deg] = make_float4(__int_as_float(i), s1/dg, s2/dg, 0.f);
}

// ---------------- tiled fp32 GEMM: Gbf = bf16(h @ W), plus asrc/adst row dots ----------------
__global__ __launch_bounds__(256) void kgemm2(const float* __restrict__ hin,
    const float* __restrict__ W,
    const float* __restrict__ atts, const float* __restrict__ attd,
    unsigned short* __restrict__ Gbf, float* __restrict__ asrc, float* __restrict__ adst){
  __shared__ float hs[128*128];   // 64 KB, stride 128 dwords, swizzled
  int t = threadIdx.x;
  int row0 = blockIdx.x * 128;
  #pragma unroll
  for(int it=0; it<16; ++it){
    int f = it*256 + t;          // float4 index 0..4095
    int r = f >> 5;              // 32 float4-chunks per row
    int c4 = f & 31;
    int grow = row0 + r;
    float4 v = make_float4(0.f,0.f,0.f,0.f);
    if(grow < NN) v = *(const float4*)(hin + (size_t)grow*HH + c4*4);
    int sc4 = c4 ^ ((r>>3)&3);
    *(float4*)(hs + r*HH + sc4*4) = v;
  }
  __syncthreads();

  int tcg = t & 15;              // col group: cols c0..c0+7
  int trg = t >> 4;              // row group: rows r0..r0+7
  int c0  = tcg*8;
  int r0  = trg*8;
  int sw  = trg & 3;             // read-side swizzle

  float s_att[8], d_att[8];
  #pragma unroll
  for(int c=0;c<8;c++){ s_att[c]=atts[c0+c]; d_att[c]=attd[c0+c]; }

  float acc[8][8];
  #pragma unroll
  for(int r=0;r<8;r++)
    #pragma unroll
    for(int c=0;c<8;c++) acc[r][c]=0.f;

  for(int k=0;k<HH;k+=4){
    int k4 = k>>2;
    float4 hv[8];
    #pragma unroll
    for(int r=0;r<8;r++)
      hv[r] = *(const float4*)(hs + (r0+r)*HH + ((k4 ^ sw)<<2));
    #pragma unroll
    for(int kk=0;kk<4;kk++){
      float4 w0 = *(const float4*)(W + (size_t)(k+kk)*HH + c0);
      float4 w1 = *(const float4*)(W + (size_t)(k+kk)*HH + c0 + 4);
      float wz[8] = {w0.x,w0.y,w0.z,w0.w,w1.x,w1.y,w1.z,w1.w};
      #pragma unroll
      for(int r=0;r<8;r++){
        float hval = (kk==0)?hv[r].x : (kk==1)?hv[r].y : (kk==2)?hv[r].z : hv[r].w;
        #pragma unroll
        for(int c=0;c<8;c++) acc[r][c] += hval * wz[c];
      }
    }
  }

  #pragma unroll
  for(int r=0;r<8;r++){
    int grow = row0 + r0 + r;
    float ps=0.f, pd=0.f;
    #pragma unroll
    for(int c=0;c<8;c++){ ps += acc[r][c]*s_att[c]; pd += acc[r][c]*d_att[c]; }
    #pragma unroll
    for(int m=8;m>=1;m>>=1){ ps += __shfl_xor(ps,m,16); pd += __shfl_xor(pd,m,16); }
    if(grow < NN){
      uint4 o;
      o.x = (unsigned)f2bf(acc[r][0]) | ((unsigned)f2bf(acc[r][1])<<16);
      o.y = (unsigned)f2bf(acc[r][2]) | ((unsigned)f2bf(acc[r][3])<<16);
      o.z = (unsigned)f2bf(acc[r][4]) | ((unsigned)f2bf(acc[r][5])<<16);
      o.w = (unsigned)f2bf(acc[r][6]) | ((unsigned)f2bf(acc[r][7])<<16);
      *(uint4*)(Gbf + (size_t)grow*HH + c0) = o;   // 16B aligned (c0 mult of 8)
      if(tcg==0){ asrc[grow]=ps; adst[grow]=pd; }
    }
  }
}

// ---------------- GAT softmax-aggregate: ONE WAVE per dst node, no LDS/barriers ----
// lane k owns edge k (fast path len<=64); each lane accumulates 2 features.
__global__ __launch_bounds__(256) void kgat(const unsigned short* __restrict__ A,
    const float* __restrict__ asrc, const float* __restrict__ adst,
    const int* __restrict__ rowstart, const float4* __restrict__ csr,
    int etsel, const float* __restrict__ bias,
    float* __restrict__ alphabuf, int* __restrict__ srcbuf,
    float* __restrict__ Bout){
  int lane = threadIdx.x & 63;
  int wid  = threadIdx.x >> 6;
  int i = blockIdx.x*4 + wid;
  if(i >= NN) return;
  int base = rowstart[i]; int len = rowstart[i+1]-base;
  float adi = adst[i];
  float acc0=0.f, acc1=0.f;
  float den;
  if(__builtin_expect(len <= 64, 1)){
    float a = -1e30f; int s=0;
    if(lane < len){
      float4 en = csr[base+lane];
      s = __float_as_int(en.x);
      float et = etsel ? en.z : en.y;
      a = asrc[s] + adi + et;
      a = a>0.f ? a : 0.2f*a;            // leaky_relu 0.2
    }
    float m = a;
    #pragma unroll
    for(int mk=32;mk>=1;mk>>=1) m = fmaxf(m, __shfl_xor(m, mk));
    float ex = (lane<len) ? __expf(a-m) : 0.f;
    float sm = ex;
    #pragma unroll
    for(int mk=32;mk>=1;mk>>=1) sm += __shfl_xor(sm, mk);
    den = sm;
    for(int k=0;k<len;k++){
      float wk = __shfl(ex, k);
      int   sk = __shfl(s, k);
      unsigned pr = *(const unsigned*)(A + (size_t)sk*HH + lane*2);
      acc0 += wk * __uint_as_float(pr<<16);
      acc1 += wk * __uint_as_float(pr & 0xFFFF0000u);
    }
  } else {
    // rare fallback: strided two-pass with global spill
    float lm = -1e30f;
    for(int k=lane;k<len;k+=64){
      float4 en = csr[base+k];
      int s = __float_as_int(en.x);
      float et = etsel ? en.z : en.y;
      float a = asrc[s] + adi + et;
      a = a>0.f ? a : 0.2f*a;
      alphabuf[base+k]=a; srcbuf[base+k]=s;
      lm = fmaxf(lm,a);
    }
    #pragma unroll
    for(int mk=32;mk>=1;mk>>=1) lm = fmaxf(lm, __shfl_xor(lm, mk));
    float ls=0.f;
    for(int k=lane;k<len;k+=64){
      float ex = __expf(alphabuf[base+k]-lm);
      alphabuf[base+k]=ex; ls+=ex;
    }
    #pragma unroll
    for(int mk=32;mk>=1;mk>>=1) ls += __shfl_xor(ls, mk);
    den = ls;
    for(int c=0;c<len;c+=64){
      int kk = c+lane;
      float w = (kk<len)? alphabuf[base+kk] : 0.f;
      int   s = (kk<len)? srcbuf[base+kk] : 0;
      int lim = min(64, len-c);
      for(int j=0;j<lim;j++){
        float wk = __shfl(w, j);
        int   sk = __shfl(s, j);
        unsigned pr = *(const unsigned*)(A + (size_t)sk*HH + lane*2);
        acc0 += wk * __uint_as_float(pr<<16);
        acc1 += wk * __uint_as_float(pr & 0xFFFF0000u);
      }
    }
  }
  float inv = 1.f/den;
  float2 bb = *(const float2*)(bias + lane*2);
  float2 o;
  o.x = fmaxf(acc0*inv + bb.x, 0.f);
  o.y = fmaxf(acc1*inv + bb.y, 0.f);
  *(float2*)(Bout + (size_t)i*HH + lane*2) = o;
}

// ---------------- column mean partials ----------------
__global__ __launch_bounds__(128) void khg(const float* __restrict__ B, float* hgsum){
  int f=threadIdx.x; int b=blockIdx.x; int nb=gridDim.x;
  int chunk=(NN+nb-1)/nb;
  int i0=b*chunk, i1=min(i0+chunk, NN);
  float s=0.f;
  for(int i=i0;i<i1;i++) s += B[(size_t)i*HH+f];
  atomicAdd(&hgsum[f], s);
}

// ---------------- tiny decoder, single block ----------------
__global__ __launch_bounds__(256) void kdec(const float* __restrict__ hgsum, const float* __restrict__ eps,
   const float* muW,const float* mub,const float* lvW,const float* lvb,
   const float* decW,const float* decb,
   const float* aW1,const float* ab1,const float* aW2,const float* ab2,
   const float* nW1,const float* nb1,const float* nW2,const float* nb2,
   float* out, float* rowadj, float* rownodes){
  __shared__ float hg[HH], z[LATD], hd[HH], t1[HH], t2[HH];
  int t=threadIdx.x;
  if(t<HH) hg[t]=hgsum[t]*(1.0f/NN);
  __syncthreads();
  if(t<LATD){
    float mu=mub[t], lv=lvb[t];
    for(int k=0;k<HH;k++){ mu += hg[k]*muW[k*LATD+t]; lv += hg[k]*lvW[k*LATD+t]; }
    out[MU_OFF+t]=mu; out[LV_OFF+t]=lv;
    z[t]=mu + eps[t]*expf(0.5f*lv);
  }
  __syncthreads();
  if(t<HH){
    float a=decb[t];
    for(int k=0;k<LATD;k++) a += z[k]*decW[k*HH+t];
    hd[t]=fmaxf(a,0.f);
  }
  __syncthreads();
  if(t<HH){
    float a=ab1[t];
    for(int k=0;k<HH;k++) a += hd[k]*aW1[k*HH+t];
    t1[t]=fmaxf(a,0.f);
  } else {
    int j=t-HH;
    float a=nb1[j];
    for(int k=0;k<HH;k++) a += hd[k]*nW1[k*HH+j];
    t2[j]=fmaxf(a,0.f);
  }
  __syncthreads();
  for(int j=t;j<MAXNN;j+=256){
    float a=ab2[j];
    for(int k=0;k<HH;k++) a += t1[k]*aW2[k*MAXNN+j];
    rowadj[j]=a;
  }
  if(t<HH){
    float a=nb2[t];
    for(int k=0;k<HH;k++) a += t2[k]*nW2[k*HH+t];
    rownodes[t]=a;
  }
}

// ---------------- broadcast the two decoder rows over all N nodes ----------------
__global__ __launch_bounds__(256) void kbcast(const float* __restrict__ rowadj,
                                              const float* __restrict__ rownodes,
                                              float* __restrict__ out){
  __shared__ float row[MAXNN+HH];
  int t=threadIdx.x;
  if(t<MAXNN) row[t]=rowadj[t];
  if(t<HH) row[MAXNN+t]=rownodes[t];
  __syncthreads();
  int stride=gridDim.x*blockDim.x;
  for(int idx=blockIdx.x*blockDim.x+t; idx<OUT_TOT; idx+=stride){
    if(idx<ADJ_TOT) out[idx]=row[idx%MAXNN];
    else { int j=(idx-ADJ_TOT)&(HH-1); out[idx]=row[MAXNN+j]; }
  }
}

extern "C" void kernel_launch(void* const* d_in, const int* in_sizes, int n_in,
                              void* d_out, int out_size, void* d_ws, size_t ws_size,
                              hipStream_t stream){
  const float* x   = (const float*)d_in[0];
  const int*   ei  = (const int*)d_in[1];
  const float* ea  = (const float*)d_in[2];
  const float* eps = (const float*)d_in[3];
  const float* W1  =(const float*)d_in[5];
  const float* as1 =(const float*)d_in[6];
  const float* ad1 =(const float*)d_in[7];
  const float* We1 =(const float*)d_in[8];
  const float* ae1 =(const float*)d_in[9];
  const float* b1  =(const float*)d_in[10];
  const float* W2  =(const float*)d_in[11];
  const float* as2 =(const float*)d_in[12];
  const float* ad2 =(const float*)d_in[13];
  const float* We2 =(const float*)d_in[14];
  const float* ae2 =(const float*)d_in[15];
  const float* b2  =(const float*)d_in[16];
  const float* muW =(const float*)d_in[17];
  const float* mub =(const float*)d_in[18];
  const float* lvW =(const float*)d_in[19];
  const float* lvb =(const float*)d_in[20];
  const float* decW=(const float*)d_in[21];
  const float* decb=(const float*)d_in[22];
  const float* aW1 =(const float*)d_in[23];
  const float* ab1 =(const float*)d_in[24];
  const float* aW2 =(const float*)d_in[25];
  const float* ab2 =(const float*)d_in[26];
  const float* nW1 =(const float*)d_in[27];
  const float* nb1 =(const float*)d_in[28];
  const float* nW2 =(const float*)d_in[29];
  const float* nb2 =(const float*)d_in[30];
  float* out=(float*)d_out;

  char* w=(char*)d_ws;
  unsigned short* Abf = (unsigned short*)w; w += (size_t)NN*HH*2;
  float*  Bb       = (float*)w;  w += (size_t)NN*HH*4;
  float4* csr      = (float4*)w; w += (size_t)EF*16;
  float*  alphabuf = (float*)w;  w += (size_t)EF*4;
  int*    srcbuf   = (int*)w;    w += (size_t)EF*4;
  int*    rowstart = (int*)w;    w += (size_t)(NN+1)*4;
  int*    fill     = (int*)w;    w += (size_t)NN*4;
  int*    ideg     = (int*)w;    w += (size_t)NN*4;
  float*  asrc     = (float*)w;  w += (size_t)NN*4;
  float*  adst     = (float*)w;  w += (size_t)NN*4;
  float*  hgsum    = (float*)w;  w += 128*4;
  float*  wa1      = (float*)w;  w += 16*4;
  float*  wa2      = (float*)w;  w += 16*4;
  float*  rowadj   = (float*)w;  w += 256*4;
  float*  rownodes = (float*)w;  w += 128*4;
  int*    blocksum = (int*)w;    w += 64*4;
  int*    blockoff = (int*)w;    w += 64*4;

  int nb = (NN+1023)/1024; // 49
  int gemmblocks = (NN+127)/128; // 391
  int gatblocks  = (NN+3)/4;     // 12500

  hipLaunchKernelGGL(kinit, dim3((NN+255)/256), dim3(256), 0, stream, ideg, fill, hgsum);
  hipLaunchKernelGGL(kwa, dim3(1), dim3(64), 0, stream, We1, ae1, We2, ae2, wa1, wa2);
  hipLaunchKernelGGL(kdeg, dim3((EE+255)/256), dim3(256), 0, stream, ei, ideg);
  hipLaunchKernelGGL(kscan1, dim3(nb), dim3(1024), 0, stream, ideg, rowstart, blocksum);
  hipLaunchKernelGGL(kscan2, dim3(1), dim3(64), 0, stream, blocksum, blockoff, nb);
  hipLaunchKernelGGL(kscan3, dim3((NN+255)/256), dim3(256), 0, stream, rowstart, blockoff, nb);
  hipLaunchKernelGGL(kscatter, dim3((EE+255)/256), dim3(256), 0, stream,
                     ei, ea, wa1, wa2, rowstart, fill, csr);
  hipLaunchKernelGGL(kself, dim3((NN+255)/256), dim3(256), 0, stream, rowstart, ideg, csr);
  // layer 1
  hipLaunchKernelGGL(kgemm2, dim3(gemmblocks), dim3(256), 0, stream, x,  W1, as1, ad1, Abf, asrc, adst);
  hipLaunchKernelGGL(kgat,  dim3(gatblocks), dim3(256), 0, stream, Abf, asrc, adst, rowstart, csr, 0, b1, alphabuf, srcbuf, Bb);
  // layer 2
  hipLaunchKernelGGL(kgemm2, dim3(gemmblocks), dim3(256), 0, stream, Bb, W2, as2, ad2, Abf, asrc, adst);
  hipLaunchKernelGGL(kgat,  dim3(gatblocks), dim3(256), 0, stream, Abf, asrc, adst, rowstart, csr, 1, b2, alphabuf, srcbuf, Bb);
  // graph embedding + decoder + broadcast
  hipLaunchKernelGGL(khg,   dim3(256), dim3(128), 0, stream, Bb, hgsum);
  hipLaunchKernelGGL(kdec,  dim3(1), dim3(256), 0, stream, hgsum, eps,
                     muW,mub,lvW,lvb,decW,decb,aW1,ab1,aW2,ab2,nW1,nb1,nW2,nb2,
                     out, rowadj, rownodes);
  hipLaunchKernelGGL(kbcast, dim3(2048), dim3(256), 0, stream, rowadj, rownodes, out);
}

// Round 6
// 509.155 us; speedup vs baseline: 1.5794x; 1.1151x over previous
//
#include <hip/hip_runtime.h>
#include <math.h>

#define NN   50000
#define EE   800000
#define EF   850000   // EE + NN self loops
#define HH   128
#define FE   16
#define LATD 64
#define MAXNN 200

#define ADJ_TOT   10000000   // NN*MAXNN
#define NODES_TOT 6400000    // NN*HH
#define OUT_TOT   16400000   // ADJ_TOT + NODES_TOT
#define MU_OFF    16400000
#define LV_OFF    16400064

__device__ __forceinline__ unsigned short f2bf(float f){
  unsigned int u = __float_as_uint(f);
  unsigned int r = (u + 0x7FFFu + ((u>>16)&1u)) >> 16;   // RNE
  return (unsigned short)r;
}
__device__ __forceinline__ float bf2f(unsigned short h){
  return __uint_as_float(((unsigned int)h)<<16);
}

// ---------------- init ----------------
__global__ void kinit(int* ideg, int* fill, float* hgsum){
  int i = blockIdx.x*blockDim.x + threadIdx.x;
  if(i < NN){ ideg[i]=0; fill[i]=0; }
  if(i < HH) hgsum[i]=0.f;
}

// wa[f] = sum_j We[f][j]*att_e[j]   (fold edge-MLP into 16-vector)
__global__ void kwa(const float* We1, const float* ae1, const float* We2, const float* ae2,
                    float* wa1, float* wa2){
  int t = threadIdx.x;
  if(t < FE){
    float s1=0.f, s2=0.f;
    for(int j=0;j<HH;j++){ s1 += We1[t*HH+j]*ae1[j]; s2 += We2[t*HH+j]*ae2[j]; }
    wa1[t]=s1; wa2[t]=s2;
  }
}

__global__ void kdeg(const int* __restrict__ ei, int* ideg){
  int e = blockIdx.x*blockDim.x + threadIdx.x;
  if(e<EE) atomicAdd(&ideg[ei[EE+e]], 1);
}

// ---------------- exclusive scan of rowlen = ideg+1 ----------------
__global__ void kscan1(const int* __restrict__ ideg, int* rowstart, int* blocksum){
  __shared__ int sd[1024];
  int t=threadIdx.x; int i=blockIdx.x*1024+t;
  int v = (i<NN)? (ideg[i]+1) : 0;
  sd[t]=v; __syncthreads();
  for(int off=1; off<1024; off<<=1){
    int x = (t>=off)? sd[t-off] : 0;
    __syncthreads();
    sd[t] += x;
    __syncthreads();
  }
  if(i<NN) rowstart[i] = sd[t]-v;
  if(t==1023) blocksum[blockIdx.x]=sd[1023];
}
__global__ void kscan2(const int* blocksum, int* blockoff, int nb){
  if(threadIdx.x==0){
    int run=0;
    for(int b=0;b<nb;b++){ blockoff[b]=run; run+=blocksum[b]; }
    blockoff[nb]=run;
  }
}
__global__ void kscan3(int* rowstart, const int* __restrict__ blockoff, int nb){
  int i=blockIdx.x*blockDim.x+threadIdx.x;
  if(i<NN) rowstart[i]+=blockoff[i>>10];
  if(i==0) rowstart[NN]=blockoff[nb];
}

// ---------------- CSR scatter: one packed 16B entry per edge ----------------
// entry = {src (int bits), et1, et2, pad}
__global__ void kscatter(const int* __restrict__ ei, const float* __restrict__ ea,
                         const float* __restrict__ wa1, const float* __restrict__ wa2,
                         const int* __restrict__ rowstart, int* fill,
                         float4* __restrict__ csr){
  int e=blockIdx.x*blockDim.x+threadIdx.x;
  if(e>=EE) return;
  int s=ei[e], d=ei[EE+e];
  const float4* ea4 = (const float4*)(ea + (size_t)e*FE);
  float4 v0=ea4[0], v1=ea4[1], v2=ea4[2], v3=ea4[3];
  float va[16]={v0.x,v0.y,v0.z,v0.w, v1.x,v1.y,v1.z,v1.w,
                v2.x,v2.y,v2.z,v2.w, v3.x,v3.y,v3.z,v3.w};
  float d1=0.f,d2=0.f;
  #pragma unroll
  for(int f=0;f<FE;f++){ d1+=va[f]*wa1[f]; d2+=va[f]*wa2[f]; }
  int pos = rowstart[d] + atomicAdd(&fill[d],1);
  csr[pos] = make_float4(__int_as_float(s), d1, d2, 0.f);
}

// self-loop entry: et = mean of row's et values
// 16-lane group per node: coalesced reads + shfl_xor(16) reduction
__global__ __launch_bounds__(256) void kself(const int* __restrict__ rowstart,
                      const int* __restrict__ ideg,
                      float4* __restrict__ csr){
  int tid = threadIdx.x;
  int l16 = tid & 15;
  int grp = tid >> 4;               // 16 groups per block
  int i = blockIdx.x*16 + grp;
  if(i>=NN) return;
  int base = rowstart[i]; int deg = ideg[i];
  float s1=0.f, s2=0.f;
  for(int k=l16;k<deg;k+=16){ float4 en=csr[base+k]; s1+=en.y; s2+=en.z; }
  #pragma unroll
  for(int m=8;m>=1;m>>=1){ s1+=__shfl_xor(s1,m,16); s2+=__shfl_xor(s2,m,16); }
  if(l16==0){
    float dg = (float)deg; if(dg<1.f) dg=1.f;
    csr[base+deg] = make_float4(__int_as_float(i), s1/dg, s2/dg, 0.f);
  }
}

// ---------------- tiled fp32 GEMM: Gbf = bf16(h @ W), plus asrc/adst row dots ----------------
__global__ __launch_bounds__(256) void kgemm2(const float* __restrict__ hin,
    const float* __restrict__ W,
    const float* __restrict__ atts, const float* __restrict__ attd,
    unsigned short* __restrict__ Gbf, float* __restrict__ asrc, float* __restrict__ adst){
  __shared__ float hs[128*128];   // 64 KB, stride 128 dwords, swizzled
  int t = threadIdx.x;
  int row0 = blockIdx.x * 128;
  #pragma unroll
  for(int it=0; it<16; ++it){
    int f = it*256 + t;          // float4 index 0..4095
    int r = f >> 5;              // 32 float4-chunks per row
    int c4 = f & 31;
    int grow = row0 + r;
    float4 v = make_float4(0.f,0.f,0.f,0.f);
    if(grow < NN) v = *(const float4*)(hin + (size_t)grow*HH + c4*4);
    int sc4 = c4 ^ ((r>>3)&3);
    *(float4*)(hs + r*HH + sc4*4) = v;
  }
  __syncthreads();

  int tcg = t & 15;              // col group: cols c0..c0+7
  int trg = t >> 4;              // row group: rows r0..r0+7
  int c0  = tcg*8;
  int r0  = trg*8;
  int sw  = trg & 3;             // read-side swizzle

  float s_att[8], d_att[8];
  #pragma unroll
  for(int c=0;c<8;c++){ s_att[c]=atts[c0+c]; d_att[c]=attd[c0+c]; }

  float acc[8][8];
  #pragma unroll
  for(int r=0;r<8;r++)
    #pragma unroll
    for(int c=0;c<8;c++) acc[r][c]=0.f;

  for(int k=0;k<HH;k+=4){
    int k4 = k>>2;
    float4 hv[8];
    #pragma unroll
    for(int r=0;r<8;r++)
      hv[r] = *(const float4*)(hs + (r0+r)*HH + ((k4 ^ sw)<<2));
    #pragma unroll
    for(int kk=0;kk<4;kk++){
      float4 w0 = *(const float4*)(W + (size_t)(k+kk)*HH + c0);
      float4 w1 = *(const float4*)(W + (size_t)(k+kk)*HH + c0 + 4);
      float wz[8] = {w0.x,w0.y,w0.z,w0.w,w1.x,w1.y,w1.z,w1.w};
      #pragma unroll
      for(int r=0;r<8;r++){
        float hval = (kk==0)?hv[r].x : (kk==1)?hv[r].y : (kk==2)?hv[r].z : hv[r].w;
        #pragma unroll
        for(int c=0;c<8;c++) acc[r][c] += hval * wz[c];
      }
    }
  }

  #pragma unroll
  for(int r=0;r<8;r++){
    int grow = row0 + r0 + r;
    float ps=0.f, pd=0.f;
    #pragma unroll
    for(int c=0;c<8;c++){ ps += acc[r][c]*s_att[c]; pd += acc[r][c]*d_att[c]; }
    #pragma unroll
    for(int m=8;m>=1;m>>=1){ ps += __shfl_xor(ps,m,16); pd += __shfl_xor(pd,m,16); }
    if(grow < NN){
      uint4 o;
      o.x = (unsigned)f2bf(acc[r][0]) | ((unsigned)f2bf(acc[r][1])<<16);
      o.y = (unsigned)f2bf(acc[r][2]) | ((unsigned)f2bf(acc[r][3])<<16);
      o.z = (unsigned)f2bf(acc[r][4]) | ((unsigned)f2bf(acc[r][5])<<16);
      o.w = (unsigned)f2bf(acc[r][6]) | ((unsigned)f2bf(acc[r][7])<<16);
      *(uint4*)(Gbf + (size_t)grow*HH + c0) = o;   // 16B aligned (c0 mult of 8)
      if(tcg==0){ asrc[grow]=ps; adst[grow]=pd; }
    }
  }
}

// ---------------- GAT softmax-aggregate: ONE WAVE per dst node, no LDS/barriers ----
// 4-deep software-pipelined gather: 4 independent row loads in flight.
__global__ __launch_bounds__(256) void kgat(const unsigned short* __restrict__ A,
    const float* __restrict__ asrc, const float* __restrict__ adst,
    const int* __restrict__ rowstart, const float4* __restrict__ csr,
    int etsel, const float* __restrict__ bias,
    float* __restrict__ alphabuf, int* __restrict__ srcbuf,
    float* __restrict__ Bout){
  int lane = threadIdx.x & 63;
  int wid  = threadIdx.x >> 6;
  int i = blockIdx.x*4 + wid;
  if(i >= NN) return;
  int base = rowstart[i]; int len = rowstart[i+1]-base;
  float adi = adst[i];
  float acc0=0.f, acc1=0.f;
  float den;
  if(__builtin_expect(len <= 64, 1)){
    float a = -1e30f; int s=0;
    if(lane < len){
      float4 en = csr[base+lane];
      s = __float_as_int(en.x);
      float et = etsel ? en.z : en.y;
      a = asrc[s] + adi + et;
      a = a>0.f ? a : 0.2f*a;            // leaky_relu 0.2
    }
    float m = a;
    #pragma unroll
    for(int mk=32;mk>=1;mk>>=1) m = fmaxf(m, __shfl_xor(m, mk));
    float ex = (lane<len) ? __expf(a-m) : 0.f;
    float sm = ex;
    #pragma unroll
    for(int mk=32;mk>=1;mk>>=1) sm += __shfl_xor(sm, mk);
    den = sm;
    const unsigned short* Ap = A + lane*2;
    int k=0;
    for(; k+4<=len; k+=4){
      float wk0=__shfl(ex,k+0); int sk0=__shfl(s,k+0);
      float wk1=__shfl(ex,k+1); int sk1=__shfl(s,k+1);
      float wk2=__shfl(ex,k+2); int sk2=__shfl(s,k+2);
      float wk3=__shfl(ex,k+3); int sk3=__shfl(s,k+3);
      unsigned p0 = *(const unsigned*)(Ap + (size_t)sk0*HH);
      unsigned p1 = *(const unsigned*)(Ap + (size_t)sk1*HH);
      unsigned p2 = *(const unsigned*)(Ap + (size_t)sk2*HH);
      unsigned p3 = *(const unsigned*)(Ap + (size_t)sk3*HH);
      acc0 += wk0 * __uint_as_float(p0<<16);
      acc1 += wk0 * __uint_as_float(p0 & 0xFFFF0000u);
      acc0 += wk1 * __uint_as_float(p1<<16);
      acc1 += wk1 * __uint_as_float(p1 & 0xFFFF0000u);
      acc0 += wk2 * __uint_as_float(p2<<16);
      acc1 += wk2 * __uint_as_float(p2 & 0xFFFF0000u);
      acc0 += wk3 * __uint_as_float(p3<<16);
      acc1 += wk3 * __uint_as_float(p3 & 0xFFFF0000u);
    }
    for(; k<len; k++){
      float wk = __shfl(ex, k);
      int   sk = __shfl(s, k);
      unsigned pr = *(const unsigned*)(Ap + (size_t)sk*HH);
      acc0 += wk * __uint_as_float(pr<<16);
      acc1 += wk * __uint_as_float(pr & 0xFFFF0000u);
    }
  } else {
    // rare fallback: strided two-pass with global spill
    float lm = -1e30f;
    for(int k=lane;k<len;k+=64){
      float4 en = csr[base+k];
      int s = __float_as_int(en.x);
      float et = etsel ? en.z : en.y;
      float a = asrc[s] + adi + et;
      a = a>0.f ? a : 0.2f*a;
      alphabuf[base+k]=a; srcbuf[base+k]=s;
      lm = fmaxf(lm,a);
    }
    #pragma unroll
    for(int mk=32;mk>=1;mk>>=1) lm = fmaxf(lm, __shfl_xor(lm, mk));
    float ls=0.f;
    for(int k=lane;k<len;k+=64){
      float ex = __expf(alphabuf[base+k]-lm);
      alphabuf[base+k]=ex; ls+=ex;
    }
    #pragma unroll
    for(int mk=32;mk>=1;mk>>=1) ls += __shfl_xor(ls, mk);
    den = ls;
    for(int c=0;c<len;c+=64){
      int kk = c+lane;
      float w = (kk<len)? alphabuf[base+kk] : 0.f;
      int   s = (kk<len)? srcbuf[base+kk] : 0;
      int lim = min(64, len-c);
      for(int j=0;j<lim;j++){
        float wk = __shfl(w, j);
        int   sk = __shfl(s, j);
        unsigned pr = *(const unsigned*)(A + (size_t)sk*HH + lane*2);
        acc0 += wk * __uint_as_float(pr<<16);
        acc1 += wk * __uint_as_float(pr & 0xFFFF0000u);
      }
    }
  }
  float inv = 1.f/den;
  float2 bb = *(const float2*)(bias + lane*2);
  float2 o;
  o.x = fmaxf(acc0*inv + bb.x, 0.f);
  o.y = fmaxf(acc1*inv + bb.y, 0.f);
  *(float2*)(Bout + (size_t)i*HH + lane*2) = o;
}

// ---------------- column mean partials ----------------
__global__ __launch_bounds__(128) void khg(const float* __restrict__ B, float* hgsum){
  int f=threadIdx.x; int b=blockIdx.x; int nb=gridDim.x;
  int chunk=(NN+nb-1)/nb;
  int i0=b*chunk, i1=min(i0+chunk, NN);
  float s=0.f;
  for(int i=i0;i<i1;i++) s += B[(size_t)i*HH+f];
  atomicAdd(&hgsum[f], s);
}

// ---------------- tiny decoder, single block ----------------
__global__ __launch_bounds__(256) void kdec(const float* __restrict__ hgsum, const float* __restrict__ eps,
   const float* muW,const float* mub,const float* lvW,const float* lvb,
   const float* decW,const float* decb,
   const float* aW1,const float* ab1,const float* aW2,const float* ab2,
   const float* nW1,const float* nb1,const float* nW2,const float* nb2,
   float* out, float* rowadj, float* rownodes){
  __shared__ float hg[HH], z[LATD], hd[HH], t1[HH], t2[HH];
  int t=threadIdx.x;
  if(t<HH) hg[t]=hgsum[t]*(1.0f/NN);
  __syncthreads();
  if(t<LATD){
    float mu=mub[t], lv=lvb[t];
    for(int k=0;k<HH;k++){ mu += hg[k]*muW[k*LATD+t]; lv += hg[k]*lvW[k*LATD+t]; }
    out[MU_OFF+t]=mu; out[LV_OFF+t]=lv;
    z[t]=mu + eps[t]*expf(0.5f*lv);
  }
  __syncthreads();
  if(t<HH){
    float a=decb[t];
    for(int k=0;k<LATD;k++) a += z[k]*decW[k*HH+t];
    hd[t]=fmaxf(a,0.f);
  }
  __syncthreads();
  if(t<HH){
    float a=ab1[t];
    for(int k=0;k<HH;k++) a += hd[k]*aW1[k*HH+t];
    t1[t]=fmaxf(a,0.f);
  } else {
    int j=t-HH;
    float a=nb1[j];
    for(int k=0;k<HH;k++) a += hd[k]*nW1[k*HH+j];
    t2[j]=fmaxf(a,0.f);
  }
  __syncthreads();
  for(int j=t;j<MAXNN;j+=256){
    float a=ab2[j];
    for(int k=0;k<HH;k++) a += t1[k]*aW2[k*MAXNN+j];
    rowadj[j]=a;
  }
  if(t<HH){
    float a=nb2[t];
    for(int k=0;k<HH;k++) a += t2[k]*nW2[k*HH+t];
    rownodes[t]=a;
  }
}

// ---------------- broadcast the two decoder rows over all N nodes ----------------
__global__ __launch_bounds__(256) void kbcast(const float* __restrict__ rowadj,
                                              const float* __restrict__ rownodes,
                                              float* __restrict__ out){
  __shared__ float row[MAXNN+HH];
  int t=threadIdx.x;
  if(t<MAXNN) row[t]=rowadj[t];
  if(t<HH) row[MAXNN+t]=rownodes[t];
  __syncthreads();
  int stride=gridDim.x*blockDim.x;
  for(int idx=blockIdx.x*blockDim.x+t; idx<OUT_TOT; idx+=stride){
    if(idx<ADJ_TOT) out[idx]=row[idx%MAXNN];
    else { int j=(idx-ADJ_TOT)&(HH-1); out[idx]=row[MAXNN+j]; }
  }
}

extern "C" void kernel_launch(void* const* d_in, const int* in_sizes, int n_in,
                              void* d_out, int out_size, void* d_ws, size_t ws_size,
                              hipStream_t stream){
  const float* x   = (const float*)d_in[0];
  const int*   ei  = (const int*)d_in[1];
  const float* ea  = (const float*)d_in[2];
  const float* eps = (const float*)d_in[3];
  const float* W1  =(const float*)d_in[5];
  const float* as1 =(const float*)d_in[6];
  const float* ad1 =(const float*)d_in[7];
  const float* We1 =(const float*)d_in[8];
  const float* ae1 =(const float*)d_in[9];
  const float* b1  =(const float*)d_in[10];
  const float* W2  =(const float*)d_in[11];
  const float* as2 =(const float*)d_in[12];
  const float* ad2 =(const float*)d_in[13];
  const float* We2 =(const float*)d_in[14];
  const float* ae2 =(const float*)d_in[15];
  const float* b2  =(const float*)d_in[16];
  const float* muW =(const float*)d_in[17];
  const float* mub =(const float*)d_in[18];
  const float* lvW =(const float*)d_in[19];
  const float* lvb =(const float*)d_in[20];
  const float* decW=(const float*)d_in[21];
  const float* decb=(const float*)d_in[22];
  const float* aW1 =(const float*)d_in[23];
  const float* ab1 =(const float*)d_in[24];
  const float* aW2 =(const float*)d_in[25];
  const float* ab2 =(const float*)d_in[26];
  const float* nW1 =(const float*)d_in[27];
  const float* nb1 =(const float*)d_in[28];
  const float* nW2 =(const float*)d_in[29];
  const float* nb2 =(const float*)d_in[30];
  float* out=(float*)d_out;

  char* w=(char*)d_ws;
  unsigned short* Abf = (unsigned short*)w; w += (size_t)NN*HH*2;
  float*  Bb       = (float*)w;  w += (size_t)NN*HH*4;
  float4* csr      = (float4*)w; w += (size_t)EF*16;
  float*  alphabuf = (float*)w;  w += (size_t)EF*4;
  int*    srcbuf   = (int*)w;    w += (size_t)EF*4;
  int*    rowstart = (int*)w;    w += (size_t)(NN+1)*4;
  int*    fill     = (int*)w;    w += (size_t)NN*4;
  int*    ideg     = (int*)w;    w += (size_t)NN*4;
  float*  asrc     = (float*)w;  w += (size_t)NN*4;
  float*  adst     = (float*)w;  w += (size_t)NN*4;
  float*  hgsum    = (float*)w;  w += 128*4;
  float*  wa1      = (float*)w;  w += 16*4;
  float*  wa2      = (float*)w;  w += 16*4;
  float*  rowadj   = (float*)w;  w += 256*4;
  float*  rownodes = (float*)w;  w += 128*4;
  int*    blocksum = (int*)w;    w += 64*4;
  int*    blockoff = (int*)w;    w += 64*4;

  int nb = (NN+1023)/1024; // 49
  int gemmblocks = (NN+127)/128; // 391
  int gatblocks  = (NN+3)/4;     // 12500

  hipLaunchKernelGGL(kinit, dim3((NN+255)/256), dim3(256), 0, stream, ideg, fill, hgsum);
  hipLaunchKernelGGL(kwa, dim3(1), dim3(64), 0, stream, We1, ae1, We2, ae2, wa1, wa2);
  hipLaunchKernelGGL(kdeg, dim3((EE+255)/256), dim3(256), 0, stream, ei, ideg);
  hipLaunchKernelGGL(kscan1, dim3(nb), dim3(1024), 0, stream, ideg, rowstart, blocksum);
  hipLaunchKernelGGL(kscan2, dim3(1), dim3(64), 0, stream, blocksum, blockoff, nb);
  hipLaunchKernelGGL(kscan3, dim3((NN+255)/256), dim3(256), 0, stream, rowstart, blockoff, nb);
  hipLaunchKernelGGL(kscatter, dim3((EE+255)/256), dim3(256), 0, stream,
                     ei, ea, wa1, wa2, rowstart, fill, csr);
  hipLaunchKernelGGL(kself, dim3((NN+15)/16), dim3(256), 0, stream, rowstart, ideg, csr);
  // layer 1
  hipLaunchKernelGGL(kgemm2, dim3(gemmblocks), dim3(256), 0, stream, x,  W1, as1, ad1, Abf, asrc, adst);
  hipLaunchKernelGGL(kgat,  dim3(gatblocks), dim3(256), 0, stream, Abf, asrc, adst, rowstart, csr, 0, b1, alphabuf, srcbuf, Bb);
  // layer 2
  hipLaunchKernelGGL(kgemm2, dim3(gemmblocks), dim3(256), 0, stream, Bb, W2, as2, ad2, Abf, asrc, adst);
  hipLaunchKernelGGL(kgat,  dim3(gatblocks), dim3(256), 0, stream, Abf, asrc, adst, rowstart, csr, 1, b2, alphabuf, srcbuf, Bb);
  // graph embedding + decoder + broadcast
  hipLaunchKernelGGL(khg,   dim3(256), dim3(128), 0, stream, Bb, hgsum);
  hipLaunchKernelGGL(kdec,  dim3(1), dim3(256), 0, stream, hgsum, eps,
                     muW,mub,lvW,lvb,decW,decb,aW1,ab1,aW2,ab2,nW1,nb1,nW2,nb2,
                     out, rowadj, rownodes);
  hipLaunchKernelGGL(kbcast, dim3(2048), dim3(256), 0, stream, rowadj, rownodes, out);
}

// Round 7
// 481.067 us; speedup vs baseline: 1.6716x; 1.0584x over previous
//
#include <hip/hip_runtime.h>
#include <math.h>

#define NN   50000
#define EE   800000
#define EF   850000   // EE + NN self loops
#define HH   128
#define FE   16
#define LATD 64
#define MAXNN 200

#define ADJ_TOT   10000000   // NN*MAXNN
#define NODES_TOT 6400000    // NN*HH
#define OUT_TOT   16400000   // ADJ_TOT + NODES_TOT
#define MU_OFF    16400000
#define LV_OFF    16400064

__device__ __forceinline__ unsigned short f2bf(float f){
  unsigned int u = __float_as_uint(f);
  unsigned int r = (u + 0x7FFFu + ((u>>16)&1u)) >> 16;   // RNE
  return (unsigned short)r;
}
__device__ __forceinline__ float bf2f(unsigned short h){
  return __uint_as_float(((unsigned int)h)<<16);
}

// ---------------- init ----------------
__global__ void kinit(int* ideg, float* hgsum){
  int i = blockIdx.x*blockDim.x + threadIdx.x;
  if(i < NN) ideg[i]=0;
  if(i < HH) hgsum[i]=0.f;
}

// wa[f] = sum_j We[f][j]*att_e[j]   (fold edge-MLP into 16-vector)
__global__ void kwa(const float* We1, const float* ae1, const float* We2, const float* ae2,
                    float* wa1, float* wa2){
  int t = threadIdx.x;
  if(t < FE){
    float s1=0.f, s2=0.f;
    for(int j=0;j<HH;j++){ s1 += We1[t*HH+j]*ae1[j]; s2 += We2[t*HH+j]*ae2[j]; }
    wa1[t]=s1; wa2[t]=s2;
  }
}

// degree count + within-row rank (atomic return) — removes the atomic from kscatter
__global__ void kdeg(const int* __restrict__ ei, int* ideg, int* __restrict__ erank){
  int e = blockIdx.x*blockDim.x + threadIdx.x;
  if(e<EE) erank[e] = atomicAdd(&ideg[ei[EE+e]], 1);
}

// ---------------- exclusive scan of rowlen = ideg+1 ----------------
__global__ void kscan1(const int* __restrict__ ideg, int* rowstart, int* blocksum){
  __shared__ int sd[1024];
  int t=threadIdx.x; int i=blockIdx.x*1024+t;
  int v = (i<NN)? (ideg[i]+1) : 0;
  sd[t]=v; __syncthreads();
  for(int off=1; off<1024; off<<=1){
    int x = (t>=off)? sd[t-off] : 0;
    __syncthreads();
    sd[t] += x;
    __syncthreads();
  }
  if(i<NN) rowstart[i] = sd[t]-v;
  if(t==1023) blocksum[blockIdx.x]=sd[1023];
}
__global__ void kscan2(const int* blocksum, int* blockoff, int nb){
  if(threadIdx.x==0){
    int run=0;
    for(int b=0;b<nb;b++){ blockoff[b]=run; run+=blocksum[b]; }
    blockoff[nb]=run;
  }
}
__global__ void kscan3(int* rowstart, const int* __restrict__ blockoff, int nb){
  int i=blockIdx.x*blockDim.x+threadIdx.x;
  if(i<NN) rowstart[i]+=blockoff[i>>10];
  if(i==0) rowstart[NN]=blockoff[nb];
}

// ---------------- CSR scatter: one packed 16B entry per edge, NO atomic ----------------
// entry = {src (int bits), et1, et2, pad}
__global__ void kscatter(const int* __restrict__ ei, const float* __restrict__ ea,
                         const float* __restrict__ wa1, const float* __restrict__ wa2,
                         const int* __restrict__ rowstart, const int* __restrict__ erank,
                         float4* __restrict__ csr){
  int e=blockIdx.x*blockDim.x+threadIdx.x;
  if(e>=EE) return;
  int s=ei[e], d=ei[EE+e];
  const float4* ea4 = (const float4*)(ea + (size_t)e*FE);
  float4 v0=ea4[0], v1=ea4[1], v2=ea4[2], v3=ea4[3];
  float va[16]={v0.x,v0.y,v0.z,v0.w, v1.x,v1.y,v1.z,v1.w,
                v2.x,v2.y,v2.z,v2.w, v3.x,v3.y,v3.z,v3.w};
  float d1=0.f,d2=0.f;
  #pragma unroll
  for(int f=0;f<FE;f++){ d1+=va[f]*wa1[f]; d2+=va[f]*wa2[f]; }
  int pos = rowstart[d] + erank[e];
  csr[pos] = make_float4(__int_as_float(s), d1, d2, 0.f);
}

// self-loop entry: et = mean of row's et values
// 16-lane group per node: coalesced reads + shfl_xor(16) reduction
__global__ __launch_bounds__(256) void kself(const int* __restrict__ rowstart,
                      const int* __restrict__ ideg,
                      float4* __restrict__ csr){
  int tid = threadIdx.x;
  int l16 = tid & 15;
  int grp = tid >> 4;               // 16 groups per block
  int i = blockIdx.x*16 + grp;
  if(i>=NN) return;
  int base = rowstart[i]; int deg = ideg[i];
  float s1=0.f, s2=0.f;
  for(int k=l16;k<deg;k+=16){ float4 en=csr[base+k]; s1+=en.y; s2+=en.z; }
  #pragma unroll
  for(int m=8;m>=1;m>>=1){ s1+=__shfl_xor(s1,m,16); s2+=__shfl_xor(s2,m,16); }
  if(l16==0){
    float dg = (float)deg; if(dg<1.f) dg=1.f;
    csr[base+deg] = make_float4(__int_as_float(i), s1/dg, s2/dg, 0.f);
  }
}

// ---------------- tiled fp32 GEMM: Gbf = bf16(h @ W), plus asrc/adst row dots ----------------
__global__ __launch_bounds__(256) void kgemm2(const float* __restrict__ hin,
    const float* __restrict__ W,
    const float* __restrict__ atts, const float* __restrict__ attd,
    unsigned short* __restrict__ Gbf, float* __restrict__ asrc, float* __restrict__ adst){
  __shared__ float hs[128*128];   // 64 KB, stride 128 dwords, swizzled
  int t = threadIdx.x;
  int row0 = blockIdx.x * 128;
  #pragma unroll
  for(int it=0; it<16; ++it){
    int f = it*256 + t;          // float4 index 0..4095
    int r = f >> 5;              // 32 float4-chunks per row
    int c4 = f & 31;
    int grow = row0 + r;
    float4 v = make_float4(0.f,0.f,0.f,0.f);
    if(grow < NN) v = *(const float4*)(hin + (size_t)grow*HH + c4*4);
    int sc4 = c4 ^ ((r>>3)&3);
    *(float4*)(hs + r*HH + sc4*4) = v;
  }
  __syncthreads();

  int tcg = t & 15;              // col group: cols c0..c0+7
  int trg = t >> 4;              // row group: rows r0..r0+7
  int c0  = tcg*8;
  int r0  = trg*8;
  int sw  = trg & 3;             // read-side swizzle

  float s_att[8], d_att[8];
  #pragma unroll
  for(int c=0;c<8;c++){ s_att[c]=atts[c0+c]; d_att[c]=attd[c0+c]; }

  float acc[8][8];
  #pragma unroll
  for(int r=0;r<8;r++)
    #pragma unroll
    for(int c=0;c<8;c++) acc[r][c]=0.f;

  for(int k=0;k<HH;k+=4){
    int k4 = k>>2;
    float4 hv[8];
    #pragma unroll
    for(int r=0;r<8;r++)
      hv[r] = *(const float4*)(hs + (r0+r)*HH + ((k4 ^ sw)<<2));
    #pragma unroll
    for(int kk=0;kk<4;kk++){
      float4 w0 = *(const float4*)(W + (size_t)(k+kk)*HH + c0);
      float4 w1 = *(const float4*)(W + (size_t)(k+kk)*HH + c0 + 4);
      float wz[8] = {w0.x,w0.y,w0.z,w0.w,w1.x,w1.y,w1.z,w1.w};
      #pragma unroll
      for(int r=0;r<8;r++){
        float hval = (kk==0)?hv[r].x : (kk==1)?hv[r].y : (kk==2)?hv[r].z : hv[r].w;
        #pragma unroll
        for(int c=0;c<8;c++) acc[r][c] += hval * wz[c];
      }
    }
  }

  #pragma unroll
  for(int r=0;r<8;r++){
    int grow = row0 + r0 + r;
    float ps=0.f, pd=0.f;
    #pragma unroll
    for(int c=0;c<8;c++){ ps += acc[r][c]*s_att[c]; pd += acc[r][c]*d_att[c]; }
    #pragma unroll
    for(int m=8;m>=1;m>>=1){ ps += __shfl_xor(ps,m,16); pd += __shfl_xor(pd,m,16); }
    if(grow < NN){
      uint4 o;
      o.x = (unsigned)f2bf(acc[r][0]) | ((unsigned)f2bf(acc[r][1])<<16);
      o.y = (unsigned)f2bf(acc[r][2]) | ((unsigned)f2bf(acc[r][3])<<16);
      o.z = (unsigned)f2bf(acc[r][4]) | ((unsigned)f2bf(acc[r][5])<<16);
      o.w = (unsigned)f2bf(acc[r][6]) | ((unsigned)f2bf(acc[r][7])<<16);
      *(uint4*)(Gbf + (size_t)grow*HH + c0) = o;   // 16B aligned (c0 mult of 8)
      if(tcg==0){ asrc[grow]=ps; adst[grow]=pd; }
    }
  }
}

// ---------------- GAT softmax-aggregate: ONE WAVE per dst node, no LDS/barriers ----
// 4-deep software-pipelined gather: 4 independent row loads in flight.
__global__ __launch_bounds__(256) void kgat(const unsigned short* __restrict__ A,
    const float* __restrict__ asrc, const float* __restrict__ adst,
    const int* __restrict__ rowstart, const float4* __restrict__ csr,
    int etsel, const float* __restrict__ bias,
    float* __restrict__ alphabuf, int* __restrict__ srcbuf,
    float* __restrict__ Bout){
  int lane = threadIdx.x & 63;
  int wid  = threadIdx.x >> 6;
  int i = blockIdx.x*4 + wid;
  if(i >= NN) return;
  int base = rowstart[i]; int len = rowstart[i+1]-base;
  float adi = adst[i];
  float acc0=0.f, acc1=0.f;
  float den;
  if(__builtin_expect(len <= 64, 1)){
    float a = -1e30f; int s=0;
    if(lane < len){
      float4 en = csr[base+lane];
      s = __float_as_int(en.x);
      float et = etsel ? en.z : en.y;
      a = asrc[s] + adi + et;
      a = a>0.f ? a : 0.2f*a;            // leaky_relu 0.2
    }
    float m = a;
    #pragma unroll
    for(int mk=32;mk>=1;mk>>=1) m = fmaxf(m, __shfl_xor(m, mk));
    float ex = (lane<len) ? __expf(a-m) : 0.f;
    float sm = ex;
    #pragma unroll
    for(int mk=32;mk>=1;mk>>=1) sm += __shfl_xor(sm, mk);
    den = sm;
    const unsigned short* Ap = A + lane*2;
    int k=0;
    for(; k+4<=len; k+=4){
      float wk0=__shfl(ex,k+0); int sk0=__shfl(s,k+0);
      float wk1=__shfl(ex,k+1); int sk1=__shfl(s,k+1);
      float wk2=__shfl(ex,k+2); int sk2=__shfl(s,k+2);
      float wk3=__shfl(ex,k+3); int sk3=__shfl(s,k+3);
      unsigned p0 = *(const unsigned*)(Ap + (size_t)sk0*HH);
      unsigned p1 = *(const unsigned*)(Ap + (size_t)sk1*HH);
      unsigned p2 = *(const unsigned*)(Ap + (size_t)sk2*HH);
      unsigned p3 = *(const unsigned*)(Ap + (size_t)sk3*HH);
      acc0 += wk0 * __uint_as_float(p0<<16);
      acc1 += wk0 * __uint_as_float(p0 & 0xFFFF0000u);
      acc0 += wk1 * __uint_as_float(p1<<16);
      acc1 += wk1 * __uint_as_float(p1 & 0xFFFF0000u);
      acc0 += wk2 * __uint_as_float(p2<<16);
      acc1 += wk2 * __uint_as_float(p2 & 0xFFFF0000u);
      acc0 += wk3 * __uint_as_float(p3<<16);
      acc1 += wk3 * __uint_as_float(p3 & 0xFFFF0000u);
    }
    for(; k<len; k++){
      float wk = __shfl(ex, k);
      int   sk = __shfl(s, k);
      unsigned pr = *(const unsigned*)(Ap + (size_t)sk*HH);
      acc0 += wk * __uint_as_float(pr<<16);
      acc1 += wk * __uint_as_float(pr & 0xFFFF0000u);
    }
  } else {
    // rare fallback: strided two-pass with global spill
    float lm = -1e30f;
    for(int k=lane;k<len;k+=64){
      float4 en = csr[base+k];
      int s = __float_as_int(en.x);
      float et = etsel ? en.z : en.y;
      float a = asrc[s] + adi + et;
      a = a>0.f ? a : 0.2f*a;
      alphabuf[base+k]=a; srcbuf[base+k]=s;
      lm = fmaxf(lm,a);
    }
    #pragma unroll
    for(int mk=32;mk>=1;mk>>=1) lm = fmaxf(lm, __shfl_xor(lm, mk));
    float ls=0.f;
    for(int k=lane;k<len;k+=64){
      float ex = __expf(alphabuf[base+k]-lm);
      alphabuf[base+k]=ex; ls+=ex;
    }
    #pragma unroll
    for(int mk=32;mk>=1;mk>>=1) ls += __shfl_xor(ls, mk);
    den = ls;
    for(int c=0;c<len;c+=64){
      int kk = c+lane;
      float w = (kk<len)? alphabuf[base+kk] : 0.f;
      int   s = (kk<len)? srcbuf[base+kk] : 0;
      int lim = min(64, len-c);
      for(int j=0;j<lim;j++){
        float wk = __shfl(w, j);
        int   sk = __shfl(s, j);
        unsigned pr = *(const unsigned*)(A + (size_t)sk*HH + lane*2);
        acc0 += wk * __uint_as_float(pr<<16);
        acc1 += wk * __uint_as_float(pr & 0xFFFF0000u);
      }
    }
  }
  float inv = 1.f/den;
  float2 bb = *(const float2*)(bias + lane*2);
  float2 o;
  o.x = fmaxf(acc0*inv + bb.x, 0.f);
  o.y = fmaxf(acc1*inv + bb.y, 0.f);
  *(float2*)(Bout + (size_t)i*HH + lane*2) = o;
}

// ---------------- column mean: grid-strided, 512 blocks ----------------
__global__ __launch_bounds__(256) void khg(const float* __restrict__ B, float* hgsum){
  int f = threadIdx.x & 127;      // column
  int half = threadIdx.x >> 7;    // 0/1
  float s=0.f;
  for(int i = blockIdx.x*2+half; i < NN; i += gridDim.x*2)
    s += B[(size_t)i*HH + f];
  __shared__ float sd[256];
  sd[threadIdx.x]=s; __syncthreads();
  if(half==0) atomicAdd(&hgsum[f], sd[threadIdx.x]+sd[threadIdx.x+128]);
}

// ---------------- tiny decoder, single block ----------------
__global__ __launch_bounds__(256) void kdec(const float* __restrict__ hgsum, const float* __restrict__ eps,
   const float* muW,const float* mub,const float* lvW,const float* lvb,
   const float* decW,const float* decb,
   const float* aW1,const float* ab1,const float* aW2,const float* ab2,
   const float* nW1,const float* nb1,const float* nW2,const float* nb2,
   float* out, float* rowadj, float* rownodes){
  __shared__ float hg[HH], z[LATD], hd[HH], t1[HH], t2[HH];
  int t=threadIdx.x;
  if(t<HH) hg[t]=hgsum[t]*(1.0f/NN);
  __syncthreads();
  if(t<LATD){
    float mu=mub[t], lv=lvb[t];
    for(int k=0;k<HH;k++){ mu += hg[k]*muW[k*LATD+t]; lv += hg[k]*lvW[k*LATD+t]; }
    out[MU_OFF+t]=mu; out[LV_OFF+t]=lv;
    z[t]=mu + eps[t]*expf(0.5f*lv);
  }
  __syncthreads();
  if(t<HH){
    float a=decb[t];
    for(int k=0;k<LATD;k++) a += z[k]*decW[k*HH+t];
    hd[t]=fmaxf(a,0.f);
  }
  __syncthreads();
  if(t<HH){
    float a=ab1[t];
    for(int k=0;k<HH;k++) a += hd[k]*aW1[k*HH+t];
    t1[t]=fmaxf(a,0.f);
  } else {
    int j=t-HH;
    float a=nb1[j];
    for(int k=0;k<HH;k++) a += hd[k]*nW1[k*HH+j];
    t2[j]=fmaxf(a,0.f);
  }
  __syncthreads();
  for(int j=t;j<MAXNN;j+=256){
    float a=ab2[j];
    for(int k=0;k<HH;k++) a += t1[k]*aW2[k*MAXNN+j];
    rowadj[j]=a;
  }
  if(t<HH){
    float a=nb2[t];
    for(int k=0;k<HH;k++) a += t2[k]*nW2[k*HH+t];
    rownodes[t]=a;
  }
}

// ---------------- broadcast the two decoder rows over all N nodes ----------------
__global__ __launch_bounds__(256) void kbcast(const float* __restrict__ rowadj,
                                              const float* __restrict__ rownodes,
                                              float* __restrict__ out){
  __shared__ float row[MAXNN+HH];
  int t=threadIdx.x;
  if(t<MAXNN) row[t]=rowadj[t];
  if(t<HH) row[MAXNN+t]=rownodes[t];
  __syncthreads();
  int stride=gridDim.x*blockDim.x;
  for(int idx=blockIdx.x*blockDim.x+t; idx<OUT_TOT; idx+=stride){
    if(idx<ADJ_TOT) out[idx]=row[idx%MAXNN];
    else { int j=(idx-ADJ_TOT)&(HH-1); out[idx]=row[MAXNN+j]; }
  }
}

extern "C" void kernel_launch(void* const* d_in, const int* in_sizes, int n_in,
                              void* d_out, int out_size, void* d_ws, size_t ws_size,
                              hipStream_t stream){
  const float* x   = (const float*)d_in[0];
  const int*   ei  = (const int*)d_in[1];
  const float* ea  = (const float*)d_in[2];
  const float* eps = (const float*)d_in[3];
  const float* W1  =(const float*)d_in[5];
  const float* as1 =(const float*)d_in[6];
  const float* ad1 =(const float*)d_in[7];
  const float* We1 =(const float*)d_in[8];
  const float* ae1 =(const float*)d_in[9];
  const float* b1  =(const float*)d_in[10];
  const float* W2  =(const float*)d_in[11];
  const float* as2 =(const float*)d_in[12];
  const float* ad2 =(const float*)d_in[13];
  const float* We2 =(const float*)d_in[14];
  const float* ae2 =(const float*)d_in[15];
  const float* b2  =(const float*)d_in[16];
  const float* muW =(const float*)d_in[17];
  const float* mub =(const float*)d_in[18];
  const float* lvW =(const float*)d_in[19];
  const float* lvb =(const float*)d_in[20];
  const float* decW=(const float*)d_in[21];
  const float* decb=(const float*)d_in[22];
  const float* aW1 =(const float*)d_in[23];
  const float* ab1 =(const float*)d_in[24];
  const float* aW2 =(const float*)d_in[25];
  const float* ab2 =(const float*)d_in[26];
  const float* nW1 =(const float*)d_in[27];
  const float* nb1 =(const float*)d_in[28];
  const float* nW2 =(const float*)d_in[29];
  const float* nb2 =(const float*)d_in[30];
  float* out=(float*)d_out;

  char* w=(char*)d_ws;
  unsigned short* Abf = (unsigned short*)w; w += (size_t)NN*HH*2;
  float*  Bb       = (float*)w;  w += (size_t)NN*HH*4;
  float4* csr      = (float4*)w; w += (size_t)EF*16;
  float*  alphabuf = (float*)w;  w += (size_t)EF*4;
  int*    srcbuf   = (int*)w;    w += (size_t)EF*4;
  int*    erank    = (int*)w;    w += (size_t)EE*4;
  int*    rowstart = (int*)w;    w += (size_t)(NN+1)*4;
  int*    ideg     = (int*)w;    w += (size_t)NN*4;
  float*  asrc     = (float*)w;  w += (size_t)NN*4;
  float*  adst     = (float*)w;  w += (size_t)NN*4;
  float*  hgsum    = (float*)w;  w += 128*4;
  float*  wa1      = (float*)w;  w += 16*4;
  float*  wa2      = (float*)w;  w += 16*4;
  float*  rowadj   = (float*)w;  w += 256*4;
  float*  rownodes = (float*)w;  w += 128*4;
  int*    blocksum = (int*)w;    w += 64*4;
  int*    blockoff = (int*)w;    w += 64*4;

  int nb = (NN+1023)/1024; // 49
  int gemmblocks = (NN+127)/128; // 391
  int gatblocks  = (NN+3)/4;     // 12500

  hipLaunchKernelGGL(kinit, dim3((NN+255)/256), dim3(256), 0, stream, ideg, hgsum);
  hipLaunchKernelGGL(kwa, dim3(1), dim3(64), 0, stream, We1, ae1, We2, ae2, wa1, wa2);
  hipLaunchKernelGGL(kdeg, dim3((EE+255)/256), dim3(256), 0, stream, ei, ideg, erank);
  hipLaunchKernelGGL(kscan1, dim3(nb), dim3(1024), 0, stream, ideg, rowstart, blocksum);
  hipLaunchKernelGGL(kscan2, dim3(1), dim3(64), 0, stream, blocksum, blockoff, nb);
  hipLaunchKernelGGL(kscan3, dim3((NN+255)/256), dim3(256), 0, stream, rowstart, blockoff, nb);
  hipLaunchKernelGGL(kscatter, dim3((EE+255)/256), dim3(256), 0, stream,
                     ei, ea, wa1, wa2, rowstart, erank, csr);
  hipLaunchKernelGGL(kself, dim3((NN+15)/16), dim3(256), 0, stream, rowstart, ideg, csr);
  // layer 1
  hipLaunchKernelGGL(kgemm2, dim3(gemmblocks), dim3(256), 0, stream, x,  W1, as1, ad1, Abf, asrc, adst);
  hipLaunchKernelGGL(kgat,  dim3(gatblocks), dim3(256), 0, stream, Abf, asrc, adst, rowstart, csr, 0, b1, alphabuf, srcbuf, Bb);
  // layer 2
  hipLaunchKernelGGL(kgemm2, dim3(gemmblocks), dim3(256), 0, stream, Bb, W2, as2, ad2, Abf, asrc, adst);
  hipLaunchKernelGGL(kgat,  dim3(gatblocks), dim3(256), 0, stream, Abf, asrc, adst, rowstart, csr, 1, b2, alphabuf, srcbuf, Bb);
  // graph embedding + decoder + broadcast
  hipLaunchKernelGGL(khg,   dim3(512), dim3(256), 0, stream, Bb, hgsum);
  hipLaunchKernelGGL(kdec,  dim3(1), dim3(256), 0, stream, hgsum, eps,
                     muW,mub,lvW,lvb,decW,decb,aW1,ab1,aW2,ab2,nW1,nb1,nW2,nb2,
                     out, rowadj, rownodes);
  hipLaunchKernelGGL(kbcast, dim3(2048), dim3(256), 0, stream, rowadj, rownodes, out);
}